// Round 4
// baseline (337.402 us; speedup 1.0000x reference)
//
#include <hip/hip_runtime.h>
#include <stdint.h>

typedef float  f32x4  __attribute__((ext_vector_type(4)));
typedef int    i32x4  __attribute__((ext_vector_type(4)));
typedef __bf16 bf16x4 __attribute__((ext_vector_type(4)));

#define D_    1024
#define SIXD  6144
// 0.125 (1/sqrt(64)) * log2(e): folded into Q so attn P = exp2(S) directly
#define QSCALE 0.18033688011112042f

#define BAR() asm volatile("s_barrier" ::: "memory")

__device__ __forceinline__ void mfma16(const i32x4 &a, const i32x4 &b, f32x4 &c) {
  asm("v_mfma_f32_16x16x32_bf16 %0, %1, %2, %0" : "+v"(c) : "v"(a), "v"(b));
}
// accumulator pinned in AGPRs (no accvgpr ping-pong, frees arch VGPRs)
__device__ __forceinline__ void mfma16a(const i32x4 &a, const i32x4 &b, f32x4 &c) {
  asm("v_mfma_f32_16x16x32_bf16 %0, %1, %2, %0" : "+a"(c) : "v"(a), "v"(b));
}

__device__ __forceinline__ void gload_lds16(const void* g, void* l) {
  __builtin_amdgcn_global_load_lds(
      (const __attribute__((address_space(1))) uint32_t*)g,
      (__attribute__((address_space(3))) uint32_t*)l, 16, 0, 0);
}

// =====================================================================
// cond: cproj[b, :] = silu(c[b,:]) @ Wc + bc   (grid 192, 32 cols/block)
// =====================================================================
__global__ __launch_bounds__(256)
void cond_gemm(const float* __restrict__ c, const float* __restrict__ Wc,
               const float* __restrict__ bc, float* __restrict__ cproj)
{
  __shared__ float sc[4096];
  __shared__ float tp[8][4][32];
  int tid = threadIdx.x;
  for (int i = tid; i < 4096; i += 256) {
    float v = c[i];
    sc[i] = v / (1.f + __expf(-v));
  }
  __syncthreads();
  int colo = tid & 31, kseg = tid >> 5;
  int col = blockIdx.x * 32 + colo;
  float a0 = 0.f, a1 = 0.f, a2 = 0.f, a3 = 0.f;
  for (int k = kseg * 128; k < kseg * 128 + 128; k++) {
    float w = Wc[(size_t)k * SIXD + col];
    a0 += sc[k] * w; a1 += sc[1024 + k] * w;
    a2 += sc[2048 + k] * w; a3 += sc[3072 + k] * w;
  }
  tp[kseg][0][colo] = a0; tp[kseg][1][colo] = a1;
  tp[kseg][2][colo] = a2; tp[kseg][3][colo] = a3;
  __syncthreads();
  if (kseg == 0) {
#pragma unroll
    for (int b = 0; b < 4; b++) {
      float s = bc[col];
#pragma unroll
      for (int g = 0; g < 8; g++) s += tp[g][b][colo];
      cproj[b * SIXD + col] = s;
    }
  }
}

// =====================================================================
// all 4 weight transposes in one kernel, 64x64 tiles, float4 reads
// grid 3072: [0,768) Wqkv | [768,1024) Wo | [1024,2048) W1 | [2048,3072) W2
// =====================================================================
__global__ __launch_bounds__(256)
void transpose_all(const float* __restrict__ Wqkv, const float* __restrict__ Wo,
                   const float* __restrict__ W1, const float* __restrict__ W2,
                   __bf16* __restrict__ Wqkvt, __bf16* __restrict__ Wot,
                   __bf16* __restrict__ W1t, __bf16* __restrict__ W2t)
{
  __shared__ __bf16 t[64][65];
  int bid = blockIdx.x;
  const float* W; __bf16* Wt; int Kdim, Ndim, lb;
  if (bid < 768)       { W = Wqkv; Wt = Wqkvt; Kdim = 1024; Ndim = 3072; lb = bid; }
  else if (bid < 1024) { W = Wo;   Wt = Wot;   Kdim = 1024; Ndim = 1024; lb = bid - 768; }
  else if (bid < 2048) { W = W1;   Wt = W1t;   Kdim = 1024; Ndim = 4096; lb = bid - 1024; }
  else                 { W = W2;   Wt = W2t;   Kdim = 4096; Ndim = 1024; lb = bid - 2048; }
  int ntn = Ndim >> 6;
  int kt = lb / ntn, nt = lb % ntn;
  int tid = threadIdx.x;
  const float* src = W + (size_t)(kt * 64) * Ndim + nt * 64;
#pragma unroll
  for (int i = 0; i < 4; i++) {
    int k = i * 16 + (tid >> 4);
    int c4 = tid & 15;
    float4 v = ((const float4*)(src + (size_t)k * Ndim))[c4];
    t[k][c4 * 4 + 0] = (__bf16)v.x; t[k][c4 * 4 + 1] = (__bf16)v.y;
    t[k][c4 * 4 + 2] = (__bf16)v.z; t[k][c4 * 4 + 3] = (__bf16)v.w;
  }
  __syncthreads();
  __bf16* dst = Wt + (size_t)(nt * 64) * Kdim + kt * 64;
  int n = tid >> 2, ks = (tid & 3) * 16;
  bf16x4 o0, o1, o2, o3;
#pragma unroll
  for (int j = 0; j < 4; j++) {
    o0[j] = t[ks + j][n];      o1[j] = t[ks + 4 + j][n];
    o2[j] = t[ks + 8 + j][n];  o3[j] = t[ks + 12 + j][n];
  }
  __bf16* dp = dst + (size_t)n * Kdim + ks;
  *(bf16x4*)(dp) = o0; *(bf16x4*)(dp + 4) = o1;
  *(bf16x4*)(dp + 8) = o2; *(bf16x4*)(dp + 12) = o3;
}

// =====================================================================
// V-part of qkv (bf16) -> Vt[(b*16+h)*64 + d][n]
// =====================================================================
__global__ __launch_bounds__(256)
void transpose_v(const __bf16* __restrict__ qkv, __bf16* __restrict__ Vt)
{
  __shared__ __bf16 t[32][33];
  int bid = blockIdx.x;
  int dt = bid & 1, nt = (bid >> 1) & 31, bh = bid >> 6;
  int b = bh >> 4, h = bh & 15;
  int x = threadIdx.x & 31, yq = threadIdx.x >> 5;
  const __bf16* src = qkv + ((size_t)(b * 1024 + nt * 32)) * 3072 + 2048 + h * 64 + dt * 32;
#pragma unroll
  for (int i = 0; i < 4; i++) {
    int row = yq * 4 + i;
    t[row][x] = src[(size_t)row * 3072 + x];
  }
  __syncthreads();
  __bf16* dst = Vt + ((size_t)(bh * 64 + dt * 32)) * 1024 + nt * 32;
#pragma unroll
  for (int i = 0; i < 4; i++) {
    int drow = yq * 4 + i;
    dst[(size_t)drow * 1024 + x] = t[x][drow];
  }
}

// =====================================================================
// fused LayerNorm + modulate, fp32 in -> bf16 out
// =====================================================================
__global__ __launch_bounds__(256)
void ln_mod(const float* __restrict__ X, const float* __restrict__ cproj,
            int shift_off, int scale_off, __bf16* __restrict__ Out)
{
  int row = blockIdx.x;
  int b = row >> 10;
  int tid = threadIdx.x;
  const float4* xr = (const float4*)(X + (size_t)row * D_);
  float4 v = xr[tid];
  float s  = v.x + v.y + v.z + v.w;
  float s2 = v.x * v.x + v.y * v.y + v.z * v.z + v.w * v.w;
#pragma unroll
  for (int off = 1; off < 64; off <<= 1) {
    s  += __shfl_xor(s,  off, 64);
    s2 += __shfl_xor(s2, off, 64);
  }
  __shared__ float red[8];
  int wave = tid >> 6, lane = tid & 63;
  if (lane == 0) { red[wave] = s; red[4 + wave] = s2; }
  __syncthreads();
  s  = red[0] + red[1] + red[2] + red[3];
  s2 = red[4] + red[5] + red[6] + red[7];
  float mean = s * (1.f / D_);
  float var  = s2 * (1.f / D_) - mean * mean;
  float rstd = rsqrtf(var + 1e-6f);
  const float4* sh = (const float4*)(cproj + b * SIXD + shift_off);
  const float4* sc = (const float4*)(cproj + b * SIXD + scale_off);
  float4 shv = sh[tid], scv = sc[tid];
  bf16x4 o;
  o[0] = (__bf16)((v.x - mean) * rstd * (1.f + scv.x) + shv.x);
  o[1] = (__bf16)((v.y - mean) * rstd * (1.f + scv.y) + shv.y);
  o[2] = (__bf16)((v.z - mean) * rstd * (1.f + scv.z) + shv.z);
  o[3] = (__bf16)((v.w - mean) * rstd * (1.f + scv.w) + shv.w);
  *(bf16x4*)(Out + (size_t)row * D_ + tid * 4) = o;
}

// =====================================================================
// bf16 MFMA GEMM, C = A(MxK) @ Bt(NxK)^T, 128x128 tile, BK=32.
// NBUF-deep LDS pipeline, XCD-swizzled grid. (Kept for Wo: N=1024)
// EPI 1: f32 = resid + gate * (acc + bias)
// =====================================================================
template<int EPI, int NBUF>
__global__ __launch_bounds__(256)
void gemm_bt(const __bf16* __restrict__ A, const __bf16* __restrict__ Bt,
             const float* __restrict__ bias, const float* __restrict__ cproj,
             int gate_off, const float* __restrict__ resid,
             void* __restrict__ Cout, void* __restrict__ Cout2,
             void* __restrict__ Cout3, void* __restrict__ Cout4,
             int M, int N, int K, int SK)
{
  __shared__ __align__(16) __bf16 As[NBUF * 128 * 32];
  __shared__ __align__(16) __bf16 Bs[NBUF * 128 * 32];
  const int PD = NBUF - 1;
  int tilesN = N >> 7, tilesM = M >> 7;
  int npersk = tilesM * tilesN;
  int sk = blockIdx.x / npersk;
  int rest = blockIdx.x % npersk;
  int cpx = npersk >> 3;
  rest = (rest & 7) * cpx + (rest >> 3);   // XCD-contiguous chunks
  int bm = rest / tilesN, bn = rest % tilesN;
  int Klen = K / SK, Kstart = sk * Klen;

  int tid = threadIdx.x;
  int lane = tid & 63, wave = tid >> 6;
  int lr = lane & 15, lg = lane >> 4;
  int wm = (wave >> 1) << 6, wn = (wave & 1) << 6;

  f32x4 acc[4][4] = {};

  int sr = tid >> 2, skb = tid & 3;
  int scol = ((skb ^ ((sr >> 1) & 3)) * 8);
  const __bf16* pa = A + (size_t)((bm << 7) + sr) * K + Kstart + scol;
  const __bf16* pb = Bt + (size_t)((bn << 7) + sr) * K + Kstart + scol;
  const size_t rstep = (size_t)64 * K;
  __bf16* la = As + tid * 8;
  __bf16* lb = Bs + tid * 8;

  auto STAGE = [&](int buf, int k0) {
    int bo = buf * 4096;
    gload_lds16(pa + k0, la + bo);
    gload_lds16(pa + rstep + k0, la + bo + 2048);
    gload_lds16(pb + k0, lb + bo);
    gload_lds16(pb + rstep + k0, lb + bo + 2048);
  };

  int nt = Klen >> 5;
#pragma unroll
  for (int p = 0; p < PD; p++) STAGE(p, p * 32);

  for (int t = 0; t < nt; t++) {
    if (t + PD < nt) STAGE((t + PD) % NBUF, (t + PD) * 32);
    int ahead = nt - 1 - t; if (ahead > PD) ahead = PD;
    if (ahead >= 3)      asm volatile("s_waitcnt vmcnt(12)" ::: "memory");
    else if (ahead == 2) asm volatile("s_waitcnt vmcnt(8)" ::: "memory");
    else if (ahead == 1) asm volatile("s_waitcnt vmcnt(4)" ::: "memory");
    else                 asm volatile("s_waitcnt vmcnt(0)" ::: "memory");
    BAR();
    const __bf16* Ac = As + (t % NBUF) * 4096;
    const __bf16* Bc = Bs + (t % NBUF) * 4096;
    i32x4 af[4], bfv[4];
#pragma unroll
    for (int m = 0; m < 4; m++) {
      int row = wm + m * 16 + lr;
      af[m] = *(const i32x4*)(Ac + row * 32 + ((lg ^ ((row >> 1) & 3)) * 8));
    }
#pragma unroll
    for (int n = 0; n < 4; n++) {
      int row = wn + n * 16 + lr;
      bfv[n] = *(const i32x4*)(Bc + row * 32 + ((lg ^ ((row >> 1) & 3)) * 8));
    }
    asm volatile("s_waitcnt lgkmcnt(0)" ::: "memory");
    __builtin_amdgcn_sched_barrier(0);
    BAR();
    __builtin_amdgcn_s_setprio(1);
#pragma unroll
    for (int m = 0; m < 4; m++)
#pragma unroll
      for (int n = 0; n < 4; n++)
        mfma16(af[m], bfv[n], acc[m][n]);
    __builtin_amdgcn_s_setprio(0);
  }
  asm volatile("s_waitcnt vmcnt(0)" ::: "memory");
  asm volatile("s_nop 7\n\ts_nop 7" ::);

  __bf16* Pp = nullptr;
  if (EPI == 3) {
    if (sk == 0)      Pp = (__bf16*)Cout;
    else if (sk == 1) Pp = (__bf16*)Cout2;
    else if (sk == 2) Pp = (__bf16*)Cout3;
    else              Pp = (__bf16*)Cout4;
  }

  int row0 = (bm << 7) + wm;
  int col0 = (bn << 7) + wn;
#pragma unroll
  for (int m = 0; m < 4; m++) {
#pragma unroll
    for (int n = 0; n < 4; n++) {
      int cc = col0 + n * 16 + lr;
      float bv = (EPI == 3) ? 0.f : bias[cc];
#pragma unroll
      for (int r = 0; r < 4; r++) {
        int row = row0 + m * 16 + (lg << 2) + r;
        float v = acc[m][n][r] + bv;
        size_t idx = (size_t)row * N + cc;
        if (EPI == 0) {
          ((__bf16*)Cout)[idx] = (__bf16)v;
        } else if (EPI == 1) {
          int b = row >> 10;
          float g = cproj[b * SIXD + gate_off + cc];
          ((float*)Cout)[idx] = resid[idx] + g * v;
        } else if (EPI == 2) {
          float u = 0.7978845608028654f * (v + 0.044715f * v * v * v);
          u = fminf(fmaxf(u, -15.f), 15.f);
          float e = __expf(2.f * u);
          float th = (e - 1.f) / (e + 1.f);
          ((__bf16*)Cout)[idx] = (__bf16)(0.5f * v * (1.f + th));
        } else if (EPI == 4) {
          float scq = (cc < 1024) ? QSCALE : 1.f;
          ((__bf16*)Cout)[idx] = (__bf16)(v * scq);
        } else {
          Pp[idx] = (__bf16)v;
        }
      }
    }
  }
}

// =====================================================================
// 256x256-tile 8-phase bf16 MFMA GEMM — faithful m201-template port.
// BK=64, 8 waves (2M x 4N), 512 threads, 128 KiB LDS (2 dbuf).
// Per wave: 128x64 output, acc[8][4] f32x4 in AGPRs.
// Per K-tile: 4 quadrant-phases, each:
//   {ds_read THIS phase's frags; stage 2 gloads (ring); [lgkmcnt(8) if 12
//    reads]; BAR; lgkmcnt(0); setprio(1); 16 MFMA; setprio(0); BAR}
// Quadrants: Q1 m0-3 x n0-1 (reads A m0-3 + B n0-1), Q2 m0-3 x n2-3
// (reads B n2-3), Q3 m4-7 x n2-3 (reads A m4-7), Q4 m4-7 x n0-1 (reads 0).
// Staging ring (2 gloads/phase, quarter-tiles q = 64 rows):
//   Q1: A q1,q3 (t+1) | Q2: A q0,q2 (t+2) | Q3: B q0,q1 (t+2) | Q4: B q2,q3 (t+2)
// Each stage lands only after its region's reads drained (phase lgkm0+BAR).
// vmcnt(6) ONLY at Q4 (3 half-tiles in flight): retires all stages up
// through Q1's -> tile t+1 fully landed before its first read.
// Prologue: tile0 full + tile1 minus A q1,q3; vmcnt(6).
// EPI 2: bf16 = gelu_tanh(acc + bias)
// EPI 3: bf16 partial = acc -> Pk[sk]
// EPI 4: bf16 = (acc + bias) * (col<1024 ? QSCALE : 1)
// =====================================================================
template<int EPI, int NT, int KD>
__global__ __launch_bounds__(512, 2)
void gemm256(const __bf16* __restrict__ A, const __bf16* __restrict__ Bt,
             const float* __restrict__ bias,
             void* __restrict__ Cout, void* __restrict__ Cout2,
             void* __restrict__ Cout3, void* __restrict__ Cout4,
             int M, int N)
{
  __shared__ __align__(16) __bf16 As[2 * 16384];   // 2 x 256x64
  __shared__ __align__(16) __bf16 Bs[2 * 16384];
  int tilesN = N >> 8, tilesM = M >> 8;
  int npersk = tilesM * tilesN;
  int sk = blockIdx.x / npersk;
  int rest = blockIdx.x % npersk;
  int cpx = npersk >> 3;
  rest = (rest & 7) * cpx + (rest >> 3);   // XCD-contiguous chunks
  int bm = rest / tilesN, bn = rest % tilesN;
  int Kstart = sk * (NT * 64);

  int tid = threadIdx.x;
  int lane = tid & 63, wave = tid >> 6;
  int lr = lane & 15, lg = lane >> 4;
  int wr = wave >> 2, wc = wave & 3;

  f32x4 acc[8][4] = {};

  // staging: one gload covers 64 rows x 64 k; thread -> (row=tid>>3, chunk)
  int srow = tid >> 3;
  int schunk = (tid & 7) ^ (srow & 7);     // pre-swizzled global source
  const __bf16* pa = A  + (size_t)((bm << 8) + srow) * KD + Kstart + schunk * 8;
  const __bf16* pb = Bt + (size_t)((bn << 8) + srow) * KD + Kstart + schunk * 8;
  __bf16* la = As + tid * 8;
  __bf16* lb = Bs + tid * 8;

  // quarter q (64 rows) of tile t
  auto SAq = [&](int t, int q) {
    gload_lds16(pa + (size_t)(q * 64) * KD + t * 64,
                la + (t & 1) * 16384 + q * 4096);
  };
  auto SBq = [&](int t, int q) {
    gload_lds16(pb + (size_t)(q * 64) * KD + t * 64,
                lb + (t & 1) * 16384 + q * 4096);
  };

  // prologue: tile0 full (8) + tile1 minus A q1,q3 (6) -> vmcnt(6) = tile0
  SAq(0, 0); SAq(0, 1); SAq(0, 2); SAq(0, 3);
  SBq(0, 0); SBq(0, 1); SBq(0, 2); SBq(0, 3);
  SAq(1, 0); SAq(1, 2);
  SBq(1, 0); SBq(1, 1); SBq(1, 2); SBq(1, 3);
  asm volatile("s_waitcnt vmcnt(6)" ::: "memory");
  BAR();

  // ds_read addressing: row*128B + ((kchunk ^ (row&7))*16); row&7 == lr&7
  int cc0 = ((lg ^ (lr & 7)) << 4);
  int cc1 = cc0 ^ 64;
  const char* aA = (const char*)As + (wr * 128 + lr) * 128;
  const char* aB = (const char*)Bs + (wc * 64 + lr) * 128;

  i32x4 av[4][2], b0v[2][2], b1v[2][2];

#pragma unroll 2
  for (int t = 0; t < NT; t++) {
    const char* Ab = aA + (t & 1) * 32768;
    const char* Bb = aB + (t & 1) * 32768;

    // ---------- Q1: read A m0-3 + B n0-1 (12); stage A q1,q3 (t+1); MFMA m0-3 x n0-1
#pragma unroll
    for (int m = 0; m < 4; m++) {
      av[m][0] = *(const i32x4*)(Ab + m * 2048 + cc0);
      av[m][1] = *(const i32x4*)(Ab + m * 2048 + cc1);
    }
#pragma unroll
    for (int n = 0; n < 2; n++) {
      b0v[n][0] = *(const i32x4*)(Bb + n * 2048 + cc0);
      b0v[n][1] = *(const i32x4*)(Bb + n * 2048 + cc1);
    }
    if (t + 1 < NT) { SAq(t + 1, 1); SAq(t + 1, 3); }
    asm volatile("s_waitcnt lgkmcnt(8)" ::: "memory");
    BAR();
    asm volatile("s_waitcnt lgkmcnt(0)" ::: "memory");
    __builtin_amdgcn_sched_barrier(0);
    __builtin_amdgcn_s_setprio(1);
#pragma unroll
    for (int m = 0; m < 4; m++)
#pragma unroll
      for (int n = 0; n < 2; n++) {
        mfma16a(av[m][0], b0v[n][0], acc[m][n]);
        mfma16a(av[m][1], b0v[n][1], acc[m][n]);
      }
    __builtin_amdgcn_s_setprio(0);
    BAR();

    // ---------- Q2: read B n2-3 (4); stage A q0,q2 (t+2); MFMA m0-3 x n2-3
#pragma unroll
    for (int n = 0; n < 2; n++) {
      b1v[n][0] = *(const i32x4*)(Bb + 4096 + n * 2048 + cc0);
      b1v[n][1] = *(const i32x4*)(Bb + 4096 + n * 2048 + cc1);
    }
    if (t + 2 < NT) { SAq(t + 2, 0); SAq(t + 2, 2); }
    BAR();
    asm volatile("s_waitcnt lgkmcnt(0)" ::: "memory");
    __builtin_amdgcn_sched_barrier(0);
    __builtin_amdgcn_s_setprio(1);
#pragma unroll
    for (int m = 0; m < 4; m++)
#pragma unroll
      for (int n = 0; n < 2; n++) {
        mfma16a(av[m][0], b1v[n][0], acc[m][2 + n]);
        mfma16a(av[m][1], b1v[n][1], acc[m][2 + n]);
      }
    __builtin_amdgcn_s_setprio(0);
    BAR();

    // ---------- Q3: read A m4-7 (8); stage B q0,q1 (t+2); MFMA m4-7 x n2-3
#pragma unroll
    for (int m = 0; m < 4; m++) {
      av[m][0] = *(const i32x4*)(Ab + 8192 + m * 2048 + cc0);
      av[m][1] = *(const i32x4*)(Ab + 8192 + m * 2048 + cc1);
    }
    if (t + 2 < NT) { SBq(t + 2, 0); SBq(t + 2, 1); }
    BAR();
    asm volatile("s_waitcnt lgkmcnt(0)" ::: "memory");
    __builtin_amdgcn_sched_barrier(0);
    __builtin_amdgcn_s_setprio(1);
#pragma unroll
    for (int m = 0; m < 4; m++)
#pragma unroll
      for (int n = 0; n < 2; n++) {
        mfma16a(av[m][0], b1v[n][0], acc[4 + m][2 + n]);
        mfma16a(av[m][1], b1v[n][1], acc[4 + m][2 + n]);
      }
    __builtin_amdgcn_s_setprio(0);
    BAR();

    // ---------- Q4: no reads; stage B q2,q3 (t+2); vmcnt(6); MFMA m4-7 x n0-1
    if (t + 2 < NT) {
      SBq(t + 2, 2); SBq(t + 2, 3);
      asm volatile("s_waitcnt vmcnt(6)" ::: "memory");
    } else {
      asm volatile("s_waitcnt vmcnt(0)" ::: "memory");
    }
    BAR();
    __builtin_amdgcn_s_setprio(1);
#pragma unroll
    for (int m = 0; m < 4; m++)
#pragma unroll
      for (int n = 0; n < 2; n++) {
        mfma16a(av[m][0], b0v[n][0], acc[4 + m][n]);
        mfma16a(av[m][1], b0v[n][1], acc[4 + m][n]);
      }
    __builtin_amdgcn_s_setprio(0);
    BAR();
  }
  asm volatile("s_nop 7\n\ts_nop 7" ::);

  __bf16* Pp = nullptr;
  if (EPI == 3) {
    if (sk == 0)      Pp = (__bf16*)Cout;
    else if (sk == 1) Pp = (__bf16*)Cout2;
    else if (sk == 2) Pp = (__bf16*)Cout3;
    else              Pp = (__bf16*)Cout4;
  }

  int row0 = (bm << 8) + wr * 128;
  int col0 = (bn << 8) + wc * 64;
#pragma unroll
  for (int m = 0; m < 8; m++) {
#pragma unroll
    for (int n = 0; n < 4; n++) {
      int cc = col0 + n * 16 + lr;
      float bv = (EPI == 3) ? 0.f : bias[cc];
#pragma unroll
      for (int r = 0; r < 4; r++) {
        int row = row0 + m * 16 + (lg << 2) + r;
        float v = acc[m][n][r] + bv;
        size_t idx = (size_t)row * N + cc;
        if (EPI == 2) {
          float u = 0.7978845608028654f * (v + 0.044715f * v * v * v);
          u = fminf(fmaxf(u, -15.f), 15.f);
          float e = __expf(2.f * u);
          float th = (e - 1.f) / (e + 1.f);
          ((__bf16*)Cout)[idx] = (__bf16)(0.5f * v * (1.f + th));
        } else if (EPI == 4) {
          float scq = (cc < 1024) ? QSCALE : 1.f;
          ((__bf16*)Cout)[idx] = (__bf16)(v * scq);
        } else {
          Pp[idx] = (__bf16)v;
        }
      }
    }
  }
}

// =====================================================================
// W2 split-K(4) reduce, bf16 partials (4 scattered buffers):
//   Out = Out + gate[b,col] * (P0+P1+P2+P3 + bias[col])   (in place on Z)
// =====================================================================
__global__ __launch_bounds__(256)
void reduce_w2(const __bf16* __restrict__ P0, const __bf16* __restrict__ P1,
               const __bf16* __restrict__ P2, const __bf16* __restrict__ P3,
               const float* __restrict__ bias, const float* __restrict__ cproj,
               float* __restrict__ Out)
{
  int row = blockIdx.x;
  int b = row >> 10;
  int tid = threadIdx.x;
  size_t base = (size_t)row * D_ + tid * 4;
  bf16x4 a0 = *(const bf16x4*)(P0 + base);
  bf16x4 a1 = *(const bf16x4*)(P1 + base);
  bf16x4 a2 = *(const bf16x4*)(P2 + base);
  bf16x4 a3 = *(const bf16x4*)(P3 + base);
  f32x4 s;
#pragma unroll
  for (int i = 0; i < 4; i++)
    s[i] = ((float)a0[i] + (float)a1[i]) + ((float)a2[i] + (float)a3[i]);
  f32x4 bz = *(const f32x4*)(bias + tid * 4);
  f32x4 g  = *(const f32x4*)(cproj + b * SIXD + 5120 + tid * 4);
  f32x4 z  = *(const f32x4*)(Out + base);
  *(f32x4*)(Out + base) = z + g * (s + bz);
}

// =====================================================================
// flash attention, no-max softmax (Q pre-scaled so P = exp2(S)).
// 8 waves = 128 q rows of one (b,h); KVBLK=64, double-buffered staging.
// =====================================================================
__global__ __launch_bounds__(512, 4)
void attn_flash(const __bf16* __restrict__ qkv, const __bf16* __restrict__ Vt,
                __bf16* __restrict__ O)
{
  __shared__ __align__(16) __bf16 Kl[2][64 * 64];
  __shared__ __align__(16) __bf16 Vl[2][64 * 64];
  __shared__ __align__(16) __bf16 Pl[8][16 * 64];

  int bid = ((blockIdx.x & 7) << 6) | (blockIdx.x >> 3);  // XCD swizzle
  int qt = bid & 7, h = (bid >> 3) & 15, b = bid >> 7;
  int tid = threadIdx.x, wave = tid >> 6, lane = tid & 63;
  int lr = lane & 15, lg = lane >> 4;

  size_t tok0 = (size_t)b * 1024;
  int qrow = qt * 128 + wave * 16 + lr;
  const __bf16* qptr = qkv + (tok0 + qrow) * 3072 + h * 64;
  i32x4 qf0 = *(const i32x4*)(qptr + lg * 8);
  i32x4 qf1 = *(const i32x4*)(qptr + 32 + lg * 8);

  float l_acc[4] = {0.f, 0.f, 0.f, 0.f};
  f32x4 oacc[4] = {};

  const __bf16* kbase = qkv + tok0 * 3072 + 1024 + h * 64;
  const __bf16* vbase = Vt + ((size_t)(b * 16 + h) * 64) * 1024;

  int skey = tid >> 3, sdb = tid & 7;
  const __bf16* ksrc = kbase + (size_t)skey * 3072 + ((sdb ^ (skey & 7)) * 8);
  const __bf16* vsrc = vbase + (size_t)skey * 1024 + ((sdb ^ (skey & 7)) * 8);
  __bf16* klp = &Kl[0][0] + tid * 8;
  __bf16* vlp = &Vl[0][0] + tid * 8;
  __bf16* pl = &Pl[wave][0];

  auto STAGE = [&](int buf, int kk) {
    gload_lds16(ksrc + (size_t)kk * 3072, klp + buf * 4096);
    gload_lds16(vsrc + kk, vlp + buf * 4096);
  };

  STAGE(0, 0);
  int cur = 0;
  for (int k0 = 0; k0 < 1024; k0 += 64) {
    int kn = (k0 + 64 < 1024) ? (k0 + 64) : k0;
    STAGE(cur ^ 1, kn);
    asm volatile("s_waitcnt vmcnt(2)" ::: "memory");
    BAR();
    const __bf16* K_ = &Kl[cur][0];
    const __bf16* V_ = &Vl[cur][0];

    f32x4 s[4];
    __builtin_amdgcn_s_setprio(1);
#pragma unroll
    for (int n = 0; n < 4; n++) {
      int key = n * 16 + lr;
      int kx = key & 7;
      i32x4 kf0 = *(const i32x4*)(K_ + key * 64 + ((lg ^ kx) * 8));
      i32x4 kf1 = *(const i32x4*)(K_ + key * 64 + (((4 + lg) ^ kx) * 8));
      f32x4 sa = {0.f, 0.f, 0.f, 0.f};
      mfma16(qf0, kf0, sa);
      mfma16(qf1, kf1, sa);
      s[n] = sa;
    }
    __builtin_amdgcn_s_setprio(0);

#pragma unroll
    for (int n = 0; n < 4; n++)
#pragma unroll
      for (int r = 0; r < 4; r++)
        s[n][r] = exp2f(s[n][r]);
#pragma unroll
    for (int r = 0; r < 4; r++)
      l_acc[r] += (s[0][r] + s[1][r]) + (s[2][r] + s[3][r]);

#pragma unroll
    for (int n = 0; n < 4; n++)
#pragma unroll
      for (int r = 0; r < 4; r++) {
        int prow = lg * 4 + r;
        int key = n * 16 + lr;
        int idx = prow * 64 + (((key >> 3) ^ (prow & 7)) * 8) + (key & 7);
        pl[idx] = (__bf16)s[n][r];
      }
    asm volatile("s_waitcnt lgkmcnt(0)" ::: "memory");
    __builtin_amdgcn_sched_barrier(0);
    i32x4 pf0 = *(const i32x4*)(pl + lr * 64 + ((lg ^ (lr & 7)) * 8));
    i32x4 pf1 = *(const i32x4*)(pl + lr * 64 + (((4 + lg) ^ (lr & 7)) * 8));

    __builtin_amdgcn_s_setprio(1);
#pragma unroll
    for (int dt = 0; dt < 4; dt++) {
      int vrow = dt * 16 + lr, rx = vrow & 7;
      i32x4 vf0 = *(const i32x4*)(V_ + vrow * 64 + ((lg ^ rx) * 8));
      i32x4 vf1 = *(const i32x4*)(V_ + vrow * 64 + (((4 + lg) ^ rx) * 8));
      mfma16(pf0, vf0, oacc[dt]);
      mfma16(pf1, vf1, oacc[dt]);
    }
    __builtin_amdgcn_s_setprio(0);
    asm volatile("s_waitcnt lgkmcnt(0)" ::: "memory");
    __builtin_amdgcn_sched_barrier(0);
    BAR();
    cur ^= 1;
  }
  asm volatile("s_waitcnt vmcnt(0)" ::: "memory");
  asm volatile("s_nop 7\n\ts_nop 7" ::);

  float rinv[4];
#pragma unroll
  for (int r = 0; r < 4; r++) {
    float v = l_acc[r];
#pragma unroll
    for (int off = 1; off < 16; off <<= 1) v += __shfl_xor(v, off, 64);
    rinv[r] = 1.f / v;
  }

  int orow = qt * 128 + wave * 16 + (lg << 2);
#pragma unroll
  for (int dt = 0; dt < 4; dt++)
#pragma unroll
    for (int r = 0; r < 4; r++) {
      float v = oacc[dt][r] * rinv[r];
      O[(tok0 + orow + r) * 1024 + h * 64 + dt * 16 + lr] = (__bf16)v;
    }
}

// =====================================================================
// fused: self-gram(+Y) -> X' -> cross-gram -> Z -> LN+modulate -> znorm
// 4 rows per block. Writes Z (f32) and znorm (bf16); X' never stored.
// =====================================================================
__global__ __launch_bounds__(256)
void gram_fused(const float* __restrict__ X, const float* __restrict__ Y,
                const float* __restrict__ cls,
                const float* __restrict__ A_s, const float* __restrict__ B_s,
                const float* __restrict__ rms_s,
                const float* __restrict__ C_r, const float* __restrict__ D_r,
                const float* __restrict__ rms_c,
                const float* __restrict__ cproj,
                float* __restrict__ Z, __bf16* __restrict__ Znorm)
{
  __shared__ float xs[4][D_];
  __shared__ float tp[8][4][32];
  __shared__ float t1[4][32];
  __shared__ float red[4][4];
  __shared__ float red2[4][4][2];
  int row0 = blockIdx.x * 4;
  int b = row0 >> 10;
  int tid = threadIdx.x;
  int wv = tid >> 6;

  f32x4 cv = *(const f32x4*)(cls + (size_t)b * D_ + tid * 4);
  f32x4 yv[4];
#pragma unroll
  for (int rr = 0; rr < 4; rr++) {
    ((f32x4*)xs[rr])[tid] = *(const f32x4*)(X + (size_t)(row0 + rr) * D_ + tid * 4);
    yv[rr] = *(const f32x4*)(Y + (size_t)(row0 + rr) * D_ + tid * 4);
  }
  __syncthreads();

  // ---- stage 1: t1 = x @ A_s ----
  {
    int r = tid & 31, seg = tid >> 5;
    float a0 = 0.f, a1 = 0.f, a2 = 0.f, a3 = 0.f;
    const float* ap = A_s + r;
    for (int d = seg * 128; d < seg * 128 + 128; d++) {
      float w = ap[d * 32];
      a0 += xs[0][d] * w; a1 += xs[1][d] * w;
      a2 += xs[2][d] * w; a3 += xs[3][d] * w;
    }
    tp[seg][0][r] = a0; tp[seg][1][r] = a1; tp[seg][2][r] = a2; tp[seg][3][r] = a3;
  }
  __syncthreads();
  if (tid < 128) {
    int rr = tid >> 5, r = tid & 31;
    float sv = 0.f;
#pragma unroll
    for (int g = 0; g < 8; g++) sv += tp[g][rr][r];
    t1[rr][r] = sv;
  }
  __syncthreads();

  // ---- g = t1 @ B_s ; rms ; X' = scale*g*rs + Y ; pv = X' * cls ----
  f32x4 g[4] = {};
  for (int r = 0; r < 32; r++) {
    f32x4 bv = *(const f32x4*)(B_s + (size_t)r * D_ + tid * 4);
    g[0] += t1[0][r] * bv; g[1] += t1[1][r] * bv;
    g[2] += t1[2][r] * bv; g[3] += t1[3][r] * bv;
  }
  float ssl[4];
#pragma unroll
  for (int rr = 0; rr < 4; rr++)
    ssl[rr] = g[rr][0]*g[rr][0] + g[rr][1]*g[rr][1] + g[rr][2]*g[rr][2] + g[rr][3]*g[rr][3];
#pragma unroll
  for (int off = 1; off < 64; off <<= 1)
#pragma unroll
    for (int rr = 0; rr < 4; rr++) ssl[rr] += __shfl_xor(ssl[rr], off, 64);
  if ((tid & 63) == 0) {
#pragma unroll
    for (int rr = 0; rr < 4; rr++) red[wv][rr] = ssl[rr];
  }
  __syncthreads();
  {
    f32x4 scv = *(const f32x4*)(rms_s + tid * 4);
#pragma unroll
    for (int rr = 0; rr < 4; rr++) {
      float ss = red[0][rr] + red[1][rr] + red[2][rr] + red[3][rr];
      float rs = rsqrtf(ss * (1.f / D_) + 1e-6f);
      f32x4 xp = scv * g[rr] * rs + yv[rr];
      ((f32x4*)xs[rr])[tid] = xp * cv;
    }
  }
  __syncthreads();

  // ---- stage 2: t2 = (X'.cls) @ C_r ----
  {
    int r = tid & 31, seg = tid >> 5;
    float a0 = 0.f, a1 = 0.f, a2 = 0.f, a3 = 0.f;
    const float* cp = C_r + r;
    for (int d = seg * 128; d < seg * 128 + 128; d++) {
      float w = cp[d * 32];
      a0 += xs[0][d] * w; a1 += xs[1][d] * w;
      a2 += xs[2][d] * w; a3 += xs[3][d] * w;
    }
    tp[seg][0][r] = a0; tp[seg][1][r] = a1; tp[seg][2][r] = a2; tp[seg][3][r] = a3;
  }
  __syncthreads();
  if (tid < 128) {
    int rr = tid >> 5, r = tid & 31;
    float sv = 0.f;
#pragma unroll
    for (int g2i = 0; g2i < 8; g2i++) sv += tp[g2i][rr][r];
    t1[rr][r] = sv;
  }
  __syncthreads();

  // ---- g2 = t2 @ D_r ; rms -> z ----
  f32x4 g2[4] = {};
  for (int r = 0; r < 32; r++) {
    f32x4 bv = *(const f32x4*)(D_r + (size_t)r * D_ + tid * 4);
    g2[0] += t1[0][r] * bv; g2[1] += t1[1][r] * bv;
    g2[2] += t1[2][r] * bv; g2[3] += t1[3][r] * bv;
  }
#pragma unroll
  for (int rr = 0; rr < 4; rr++)
    ssl[rr] = g2[rr][0]*g2[rr][0] + g2[rr][1]*g2[rr][1] + g2[rr][2]*g2[rr][2] + g2[rr][3]*g2[rr][3];
#pragma unroll
  for (int off = 1; off < 64; off <<= 1)
#pragma unroll
    for (int rr = 0; rr < 4; rr++) ssl[rr] += __shfl_xor(ssl[rr], off, 64);
  if ((tid & 63) == 0) {
#pragma unroll
    for (int rr = 0; rr < 4; rr++) red[wv][rr] = ssl[rr];
  }
  __syncthreads();
  f32x4 z[4];
  {
    f32x4 scv = *(const f32x4*)(rms_c + tid * 4);
#pragma unroll
    for (int rr = 0; rr < 4; rr++) {
      float ss = red[0][rr] + red[1][rr] + red[2][rr] + red[3][rr];
      float rs = rsqrtf(ss * (1.f / D_) + 1e-6f);
      z[rr] = scv * g2[rr] * rs;
    }
  }

  // ---- LN + modulate of z -> znorm ----
  float s1l[4], s2l[4];
#pragma unroll
  for (int rr = 0; rr < 4; rr++) {
    s1l[rr] = z[rr][0] + z[rr][1] + z[rr][2] + z[rr][3];
    s2l[rr] = z[rr][0]*z[rr][0] + z[rr][1]*z[rr][1] + z[rr][2]*z[rr][2] + z[rr][3]*z[rr][3];
  }
#pragma unroll
  for (int off = 1; off < 64; off <<= 1)
#pragma unroll
    for (int rr = 0; rr < 4; rr++) {
      s1l[rr] += __shfl_xor(s1l[rr], off, 64);
      s2l[rr] += __shfl_xor(s2l[rr], off, 64);
    }
  if ((tid & 63) == 0) {
#pragma unroll
    for (int rr = 0; rr < 4; rr++) { red2[wv][rr][0] = s1l[rr]; red2[wv][rr][1] = s2l[rr]; }
  }
  __syncthreads();
  f32x4 shv = *(const f32x4*)(cproj + b * SIXD + 3072 + tid * 4);
  f32x4 scm = *(const f32x4*)(cproj + b * SIXD + 4096 + tid * 4);
#pragma unroll
  for (int rr = 0; rr < 4; rr++) {
    float S  = red2[0][rr][0] + red2[1][rr][0] + red2[2][rr][0] + red2[3][rr][0];
    float S2 = red2[0][rr][1] + red2[1][rr][1] + red2[2][rr][1] + red2[3][rr][1];
    float mean = S * (1.f / D_);
    float var  = S2 * (1.f / D_) - mean * mean;
    float rstd = rsqrtf(var + 1e-6f);
    f32x4 zn = (z[rr] - mean) * rstd * (scm + 1.f) + shv;
    *(f32x4*)(Z + (size_t)(row0 + rr) * D_ + tid * 4) = z[rr];
    bf16x4 o;
#pragma unroll
    for (int i = 0; i < 4; i++) o[i] = (__bf16)zn[i];
    *(bf16x4*)(Znorm + (size_t)(row0 + rr) * D_ + tid * 4) = o;
  }
}

// =====================================================================
extern "C" void kernel_launch(void* const* d_in, const int* in_sizes, int n_in,
                              void* d_out, int out_size, void* d_ws, size_t ws_size,
                              hipStream_t stream)
{
  const float* x     = (const float*)d_in[0];
  const float* c     = (const float*)d_in[1];
  const float* cls   = (const float*)d_in[2];
  const float* Wc    = (const float*)d_in[3];
  const float* bc    = (const float*)d_in[4];
  const float* Wqkv  = (const float*)d_in[5];
  const float* bqkv  = (const float*)d_in[6];
  const float* Wo    = (const float*)d_in[7];
  const float* bo    = (const float*)d_in[8];
  const float* A_s   = (const float*)d_in[9];
  const float* B_s   = (const float*)d_in[10];
  const float* rms_s = (const float*)d_in[11];
  const float* C_r   = (const float*)d_in[12];
  const float* D_r   = (const float*)d_in[13];
  const float* rms_c = (const float*)d_in[14];
  const float* W1    = (const float*)d_in[15];
  const float* b1    = (const float*)d_in[16];
  const float* W2    = (const float*)d_in[17];
  const float* b2    = (const float*)d_in[18];
  float* out = (float*)d_out;

  float* ws = (float*)d_ws;
  __bf16* Wqkvt = (__bf16*)(ws + 0);         // 3072x1024 bf16  [floats 0..1572864)
  __bf16* Wot   = (__bf16*)(ws + 1572864);   // 1024x1024       [..2097152)
  __bf16* W1t   = (__bf16*)(ws + 2097152);   // 4096x1024       [..4194304)
  __bf16* W2t   = (__bf16*)(ws + 4194304);   // 1024x4096       [..6291456)
  float*  cproj = ws + 6291456;              // 4x6144          [..6316032)
  __bf16* xnorm = (__bf16*)(ws + 6316032);   // 4096x1024 (also znorm)  [..8413184)
  __bf16* qkv   = (__bf16*)(ws + 8413184);   // 4096x3072       [..14704640)
  __bf16* Vt    = (__bf16*)(ws + 14704640);  // 64x64x1024      [..16801792)
  __bf16* h1    = (__bf16*)(ws + 8413184);   // 4096x4096 (reuses qkv+Vt)
  __bf16* attno = (__bf16*)(ws + 16801792);  // 4096x1024       [..18898944)
  float*  Ybuf  = ws + 18898944;             // 4096x1024 f32 (Y)  [..20996096)
  // W2 split-K(4) bf16 partials, 8 MB each, in regions dead at W2-GEMM time.
  // W2t [4194304..6291456) and h1 [8413184..16801792) are NOT touched.
  __bf16* P0 = (__bf16*)(ws + 0);            // over Wqkvt+Wot (dead)
  __bf16* P1 = (__bf16*)(ws + 2097152);      // over W1t (dead after W1 GEMM)
  __bf16* P2 = (__bf16*)(ws + 16801792);     // over attno (dead after Wo GEMM)
  __bf16* P3 = (__bf16*)(ws + 18898944);     // over Ybuf (dead after gram_fused)

  cond_gemm<<<192, 256, 0, stream>>>(c, Wc, bc, cproj);
  transpose_all<<<3072, 256, 0, stream>>>(Wqkv, Wo, W1, W2, Wqkvt, Wot, W1t, W2t);
  ln_mod<<<4096, 256, 0, stream>>>(x, cproj, 0, 1024, xnorm);
  gemm256<4, 16, 1024><<<192, 512, 0, stream>>>(xnorm, Wqkvt, bqkv,
                                                qkv, nullptr, nullptr, nullptr,
                                                4096, 3072);
  transpose_v<<<4096, 256, 0, stream>>>(qkv, Vt);
  attn_flash<<<512, 512, 0, stream>>>(qkv, Vt, attno);
  gemm_bt<1, 4><<<256, 256, 0, stream>>>(attno, Wot, bo, cproj, 2048, x,
                                         Ybuf, nullptr, nullptr, nullptr,
                                         4096, 1024, 1024, 1);
  gram_fused<<<1024, 256, 0, stream>>>(x, Ybuf, cls, A_s, B_s, rms_s,
                                       C_r, D_r, rms_c, cproj, out, xnorm);
  gemm256<2, 16, 1024><<<256, 512, 0, stream>>>(xnorm, W1t, b1,
                                                h1, nullptr, nullptr, nullptr,
                                                4096, 4096);
  gemm256<3, 16, 4096><<<256, 512, 0, stream>>>(h1, W2t, nullptr,
                                                P0, P1, P2, P3, 4096, 1024);
  reduce_w2<<<4096, 256, 0, stream>>>(P0, P1, P2, P3, b2, cproj, out);
}

// Round 5
// 288.923 us; speedup vs baseline: 1.1678x; 1.1678x over previous
//
#include <hip/hip_runtime.h>
#include <stdint.h>

typedef float  f32x4  __attribute__((ext_vector_type(4)));
typedef int    i32x4  __attribute__((ext_vector_type(4)));
typedef __bf16 bf16x4 __attribute__((ext_vector_type(4)));

#define D_    1024
#define SIXD  6144
// 0.125 (1/sqrt(64)) * log2(e): folded into Q so attn P = exp2(S) directly
#define QSCALE 0.18033688011112042f

#define BAR() asm volatile("s_barrier" ::: "memory")

__device__ __forceinline__ void mfma16(const i32x4 &a, const i32x4 &b, f32x4 &c) {
  asm("v_mfma_f32_16x16x32_bf16 %0, %1, %2, %0" : "+v"(c) : "v"(a), "v"(b));
}
// accumulator pinned in AGPRs (no accvgpr ping-pong, frees arch VGPRs)
__device__ __forceinline__ void mfma16a(const i32x4 &a, const i32x4 &b, f32x4 &c) {
  asm("v_mfma_f32_16x16x32_bf16 %0, %1, %2, %0" : "+a"(c) : "v"(a), "v"(b));
}

__device__ __forceinline__ void gload_lds16(const void* g, void* l) {
  __builtin_amdgcn_global_load_lds(
      (const __attribute__((address_space(1))) uint32_t*)g,
      (__attribute__((address_space(3))) uint32_t*)l, 16, 0, 0);
}

// =====================================================================
// prep: fused cond_gemm (blocks 0..191) + weight transposes (192..3263)
//  cond: cproj[b,:] = silu(c[b,:]) @ Wc + bc
//  transpose: fp32 W -> bf16 W^T, 64x64 tiles
// =====================================================================
__global__ __launch_bounds__(256)
void prep(const float* __restrict__ c, const float* __restrict__ Wc,
          const float* __restrict__ bc, float* __restrict__ cproj,
          const float* __restrict__ Wqkv, const float* __restrict__ Wo,
          const float* __restrict__ W1, const float* __restrict__ W2,
          __bf16* __restrict__ Wqkvt, __bf16* __restrict__ Wot,
          __bf16* __restrict__ W1t, __bf16* __restrict__ W2t)
{
  __shared__ float sc[4096];
  __shared__ float tp[8][4][32];
  __shared__ __bf16 tt[64][65];
  int tid = threadIdx.x;
  if (blockIdx.x < 192) {
    for (int i = tid; i < 4096; i += 256) {
      float v = c[i];
      sc[i] = v / (1.f + __expf(-v));
    }
    __syncthreads();
    int colo = tid & 31, kseg = tid >> 5;
    int col = blockIdx.x * 32 + colo;
    float a0 = 0.f, a1 = 0.f, a2 = 0.f, a3 = 0.f;
    for (int k = kseg * 128; k < kseg * 128 + 128; k++) {
      float w = Wc[(size_t)k * SIXD + col];
      a0 += sc[k] * w; a1 += sc[1024 + k] * w;
      a2 += sc[2048 + k] * w; a3 += sc[3072 + k] * w;
    }
    tp[kseg][0][colo] = a0; tp[kseg][1][colo] = a1;
    tp[kseg][2][colo] = a2; tp[kseg][3][colo] = a3;
    __syncthreads();
    if (kseg == 0) {
#pragma unroll
      for (int b = 0; b < 4; b++) {
        float s = bc[col];
#pragma unroll
        for (int g = 0; g < 8; g++) s += tp[g][b][colo];
        cproj[b * SIXD + col] = s;
      }
    }
    return;
  }
  int bid = blockIdx.x - 192;
  const float* W; __bf16* Wt; int Kdim, Ndim, lb;
  if (bid < 768)       { W = Wqkv; Wt = Wqkvt; Kdim = 1024; Ndim = 3072; lb = bid; }
  else if (bid < 1024) { W = Wo;   Wt = Wot;   Kdim = 1024; Ndim = 1024; lb = bid - 768; }
  else if (bid < 2048) { W = W1;   Wt = W1t;   Kdim = 1024; Ndim = 4096; lb = bid - 1024; }
  else                 { W = W2;   Wt = W2t;   Kdim = 4096; Ndim = 1024; lb = bid - 2048; }
  int ntn = Ndim >> 6;
  int kt = lb / ntn, nt = lb % ntn;
  const float* src = W + (size_t)(kt * 64) * Ndim + nt * 64;
#pragma unroll
  for (int i = 0; i < 4; i++) {
    int k = i * 16 + (tid >> 4);
    int c4 = tid & 15;
    float4 v = ((const float4*)(src + (size_t)k * Ndim))[c4];
    tt[k][c4 * 4 + 0] = (__bf16)v.x; tt[k][c4 * 4 + 1] = (__bf16)v.y;
    tt[k][c4 * 4 + 2] = (__bf16)v.z; tt[k][c4 * 4 + 3] = (__bf16)v.w;
  }
  __syncthreads();
  __bf16* dst = Wt + (size_t)(nt * 64) * Kdim + kt * 64;
  int n = tid >> 2, ks = (tid & 3) * 16;
  bf16x4 o0, o1, o2, o3;
#pragma unroll
  for (int j = 0; j < 4; j++) {
    o0[j] = tt[ks + j][n];      o1[j] = tt[ks + 4 + j][n];
    o2[j] = tt[ks + 8 + j][n];  o3[j] = tt[ks + 12 + j][n];
  }
  __bf16* dp = dst + (size_t)n * Kdim + ks;
  *(bf16x4*)(dp) = o0; *(bf16x4*)(dp + 4) = o1;
  *(bf16x4*)(dp + 8) = o2; *(bf16x4*)(dp + 12) = o3;
}

// =====================================================================
// V-part of qkv (bf16) -> Vt[(b*16+h)*64 + d][n]
// =====================================================================
__global__ __launch_bounds__(256)
void transpose_v(const __bf16* __restrict__ qkv, __bf16* __restrict__ Vt)
{
  __shared__ __bf16 t[32][33];
  int bid = blockIdx.x;
  int dt = bid & 1, nt = (bid >> 1) & 31, bh = bid >> 6;
  int b = bh >> 4, h = bh & 15;
  int x = threadIdx.x & 31, yq = threadIdx.x >> 5;
  const __bf16* src = qkv + ((size_t)(b * 1024 + nt * 32)) * 3072 + 2048 + h * 64 + dt * 32;
#pragma unroll
  for (int i = 0; i < 4; i++) {
    int row = yq * 4 + i;
    t[row][x] = src[(size_t)row * 3072 + x];
  }
  __syncthreads();
  __bf16* dst = Vt + ((size_t)(bh * 64 + dt * 32)) * 1024 + nt * 32;
#pragma unroll
  for (int i = 0; i < 4; i++) {
    int drow = yq * 4 + i;
    dst[(size_t)drow * 1024 + x] = t[x][drow];
  }
}

// =====================================================================
// fused LayerNorm + modulate, fp32 in -> bf16 out
// =====================================================================
__global__ __launch_bounds__(256)
void ln_mod(const float* __restrict__ X, const float* __restrict__ cproj,
            int shift_off, int scale_off, __bf16* __restrict__ Out)
{
  int row = blockIdx.x;
  int b = row >> 10;
  int tid = threadIdx.x;
  const float4* xr = (const float4*)(X + (size_t)row * D_);
  float4 v = xr[tid];
  float s  = v.x + v.y + v.z + v.w;
  float s2 = v.x * v.x + v.y * v.y + v.z * v.z + v.w * v.w;
#pragma unroll
  for (int off = 1; off < 64; off <<= 1) {
    s  += __shfl_xor(s,  off, 64);
    s2 += __shfl_xor(s2, off, 64);
  }
  __shared__ float red[8];
  int wave = tid >> 6, lane = tid & 63;
  if (lane == 0) { red[wave] = s; red[4 + wave] = s2; }
  __syncthreads();
  s  = red[0] + red[1] + red[2] + red[3];
  s2 = red[4] + red[5] + red[6] + red[7];
  float mean = s * (1.f / D_);
  float var  = s2 * (1.f / D_) - mean * mean;
  float rstd = rsqrtf(var + 1e-6f);
  const float4* sh = (const float4*)(cproj + b * SIXD + shift_off);
  const float4* sc = (const float4*)(cproj + b * SIXD + scale_off);
  float4 shv = sh[tid], scv = sc[tid];
  bf16x4 o;
  o[0] = (__bf16)((v.x - mean) * rstd * (1.f + scv.x) + shv.x);
  o[1] = (__bf16)((v.y - mean) * rstd * (1.f + scv.y) + shv.y);
  o[2] = (__bf16)((v.z - mean) * rstd * (1.f + scv.z) + shv.z);
  o[3] = (__bf16)((v.w - mean) * rstd * (1.f + scv.w) + shv.w);
  *(bf16x4*)(Out + (size_t)row * D_ + tid * 4) = o;
}

// =====================================================================
// bf16 MFMA GEMM, C = A(MxK) @ Bt(NxK)^T, 128x128 tile, BK=32.
// NBUF-deep LDS pipeline, XCD-swizzled grid. (Kept for Wo: N=1024)
// EPI 1: f32 = resid + gate * (acc + bias)
// =====================================================================
template<int EPI, int NBUF>
__global__ __launch_bounds__(256)
void gemm_bt(const __bf16* __restrict__ A, const __bf16* __restrict__ Bt,
             const float* __restrict__ bias, const float* __restrict__ cproj,
             int gate_off, const float* __restrict__ resid,
             void* __restrict__ Cout, void* __restrict__ Cout2,
             void* __restrict__ Cout3, void* __restrict__ Cout4,
             int M, int N, int K, int SK)
{
  __shared__ __align__(16) __bf16 As[NBUF * 128 * 32];
  __shared__ __align__(16) __bf16 Bs[NBUF * 128 * 32];
  const int PD = NBUF - 1;
  int tilesN = N >> 7, tilesM = M >> 7;
  int npersk = tilesM * tilesN;
  int sk = blockIdx.x / npersk;
  int rest = blockIdx.x % npersk;
  int cpx = npersk >> 3;
  rest = (rest & 7) * cpx + (rest >> 3);   // XCD-contiguous chunks
  int bm = rest / tilesN, bn = rest % tilesN;
  int Klen = K / SK, Kstart = sk * Klen;

  int tid = threadIdx.x;
  int lane = tid & 63, wave = tid >> 6;
  int lr = lane & 15, lg = lane >> 4;
  int wm = (wave >> 1) << 6, wn = (wave & 1) << 6;

  f32x4 acc[4][4] = {};

  int sr = tid >> 2, skb = tid & 3;
  int scol = ((skb ^ ((sr >> 1) & 3)) * 8);
  const __bf16* pa = A + (size_t)((bm << 7) + sr) * K + Kstart + scol;
  const __bf16* pb = Bt + (size_t)((bn << 7) + sr) * K + Kstart + scol;
  const size_t rstep = (size_t)64 * K;
  __bf16* la = As + tid * 8;
  __bf16* lb = Bs + tid * 8;

  auto STAGE = [&](int buf, int k0) {
    int bo = buf * 4096;
    gload_lds16(pa + k0, la + bo);
    gload_lds16(pa + rstep + k0, la + bo + 2048);
    gload_lds16(pb + k0, lb + bo);
    gload_lds16(pb + rstep + k0, lb + bo + 2048);
  };

  int nt = Klen >> 5;
#pragma unroll
  for (int p = 0; p < PD; p++) STAGE(p, p * 32);

  for (int t = 0; t < nt; t++) {
    if (t + PD < nt) STAGE((t + PD) % NBUF, (t + PD) * 32);
    int ahead = nt - 1 - t; if (ahead > PD) ahead = PD;
    if (ahead >= 3)      asm volatile("s_waitcnt vmcnt(12)" ::: "memory");
    else if (ahead == 2) asm volatile("s_waitcnt vmcnt(8)" ::: "memory");
    else if (ahead == 1) asm volatile("s_waitcnt vmcnt(4)" ::: "memory");
    else                 asm volatile("s_waitcnt vmcnt(0)" ::: "memory");
    BAR();
    const __bf16* Ac = As + (t % NBUF) * 4096;
    const __bf16* Bc = Bs + (t % NBUF) * 4096;
    i32x4 af[4], bfv[4];
#pragma unroll
    for (int m = 0; m < 4; m++) {
      int row = wm + m * 16 + lr;
      af[m] = *(const i32x4*)(Ac + row * 32 + ((lg ^ ((row >> 1) & 3)) * 8));
    }
#pragma unroll
    for (int n = 0; n < 4; n++) {
      int row = wn + n * 16 + lr;
      bfv[n] = *(const i32x4*)(Bc + row * 32 + ((lg ^ ((row >> 1) & 3)) * 8));
    }
    asm volatile("s_waitcnt lgkmcnt(0)" ::: "memory");
    __builtin_amdgcn_sched_barrier(0);
    BAR();
    __builtin_amdgcn_s_setprio(1);
#pragma unroll
    for (int m = 0; m < 4; m++)
#pragma unroll
      for (int n = 0; n < 4; n++)
        mfma16(af[m], bfv[n], acc[m][n]);
    __builtin_amdgcn_s_setprio(0);
  }
  asm volatile("s_waitcnt vmcnt(0)" ::: "memory");
  asm volatile("s_nop 7\n\ts_nop 7" ::);

  __bf16* Pp = nullptr;
  if (EPI == 3) {
    if (sk == 0)      Pp = (__bf16*)Cout;
    else if (sk == 1) Pp = (__bf16*)Cout2;
    else if (sk == 2) Pp = (__bf16*)Cout3;
    else              Pp = (__bf16*)Cout4;
  }

  int row0 = (bm << 7) + wm;
  int col0 = (bn << 7) + wn;
#pragma unroll
  for (int m = 0; m < 4; m++) {
#pragma unroll
    for (int n = 0; n < 4; n++) {
      int cc = col0 + n * 16 + lr;
      float bv = (EPI == 3) ? 0.f : bias[cc];
#pragma unroll
      for (int r = 0; r < 4; r++) {
        int row = row0 + m * 16 + (lg << 2) + r;
        float v = acc[m][n][r] + bv;
        size_t idx = (size_t)row * N + cc;
        if (EPI == 0) {
          ((__bf16*)Cout)[idx] = (__bf16)v;
        } else if (EPI == 1) {
          int b = row >> 10;
          float g = cproj[b * SIXD + gate_off + cc];
          ((float*)Cout)[idx] = resid[idx] + g * v;
        } else if (EPI == 2) {
          float u = 0.7978845608028654f * (v + 0.044715f * v * v * v);
          u = fminf(fmaxf(u, -15.f), 15.f);
          float e = __expf(2.f * u);
          float th = (e - 1.f) / (e + 1.f);
          ((__bf16*)Cout)[idx] = (__bf16)(0.5f * v * (1.f + th));
        } else if (EPI == 4) {
          float scq = (cc < 1024) ? QSCALE : 1.f;
          ((__bf16*)Cout)[idx] = (__bf16)(v * scq);
        } else {
          Pp[idx] = (__bf16)v;
        }
      }
    }
  }
}

// =====================================================================
// 256x256-tile bf16 MFMA GEMM, BK=32, 3-deep LDS ring (96 KiB).
// 8 waves (2M x 4N), 512 threads; per wave 128x64 out, acc[8][4] in AGPRs.
// Mechanism (m97/m114): ONE barrier + ONE counted vmcnt per K-tile, no
// lgkm drains, no sched_barrier -- reads are plain loads, the compiler
// interleaves ds_read with MFMA and inserts precise counted lgkmcnt.
// Ring makes staging WAR-free: stages for t+2 target buf (t+2)%3 which
// differs from t%3 (reads) and (t+1)%3; cross-wave WAR safe because all
// waves passed tile-(t-1)'s barrier only after their MFMAs consumed
// (= completed) the reads of buf (t-1)%3 == (t+2)%3.
// vmcnt: 4 staging lines/tile; at tile end 8 outstanding -> vmcnt(4)
// retires t+1's lines; all waves then barrier -> t+1 fully landed.
// EPI 2: bf16 = gelu_tanh(acc + bias)
// EPI 3: bf16 partial = acc -> Pk[sk]
// EPI 4: bf16 = (acc + bias) * (col<1024 ? QSCALE : 1)
// =====================================================================
template<int EPI, int NT, int KD>
__global__ __launch_bounds__(512, 2)
void gemm256(const __bf16* __restrict__ A, const __bf16* __restrict__ Bt,
             const float* __restrict__ bias,
             void* __restrict__ Cout, void* __restrict__ Cout2,
             void* __restrict__ Cout3, void* __restrict__ Cout4,
             int M, int N)
{
  __shared__ __align__(16) __bf16 As[3 * 8192];   // 3 x 256x32
  __shared__ __align__(16) __bf16 Bs[3 * 8192];
  int tilesN = N >> 8, tilesM = M >> 8;
  int npersk = tilesM * tilesN;
  int sk = blockIdx.x / npersk;
  int rest = blockIdx.x % npersk;
  int cpx = npersk >> 3;
  rest = (rest & 7) * cpx + (rest >> 3);   // XCD-contiguous chunks
  int bm = rest / tilesN, bn = rest % tilesN;
  int Kstart = sk * (NT * 32);

  int tid = threadIdx.x;
  int lane = tid & 63, wave = tid >> 6;
  int lr = lane & 15, lg = lane >> 4;
  int wr = wave >> 2, wc = wave & 3;

  f32x4 acc[8][4] = {};

  // staging: line h covers rows h*128..h*128+127 x 32 k.
  // thread -> (row = tid>>2, chunk = tid&3), pre-swizzled global source
  // (chunk ^ ((row>>1)&3)) so linear LDS == swizzled layout.
  int srow = tid >> 2;
  int schunk = (tid & 3) ^ ((srow >> 1) & 3);
  const __bf16* pa = A  + (size_t)((bm << 8) + srow) * KD + Kstart + schunk * 8;
  const __bf16* pb = Bt + (size_t)((bn << 8) + srow) * KD + Kstart + schunk * 8;
  __bf16* la = As + tid * 8;
  __bf16* lb = Bs + tid * 8;

  // stage line h (0/1) of tile t into ring slot `slot` (bf16 offset)
  auto SA = [&](int t, int h, int slot) {
    gload_lds16(pa + (size_t)(h * 128) * KD + t * 32, la + slot + h * 4096);
  };
  auto SB = [&](int t, int h, int slot) {
    gload_lds16(pb + (size_t)(h * 128) * KD + t * 32, lb + slot + h * 4096);
  };

  // prologue: tile0 -> slot0, tile1 -> slot1
  SA(0, 0, 0); SA(0, 1, 0); SB(0, 0, 0); SB(0, 1, 0);
  SA(1, 0, 8192); SA(1, 1, 8192); SB(1, 0, 8192); SB(1, 1, 8192);
  asm volatile("s_waitcnt vmcnt(4)" ::: "memory");
  BAR();

  // ds_read addressing: row*64B + ((lg ^ ((lr>>1)&3))*16)
  int cc = ((lg ^ ((lr >> 1) & 3)) << 4);
  const char* aA = (const char*)As + (wr * 128 + lr) * 64 + cc;
  const char* aB = (const char*)Bs + (wc * 64 + lr) * 64 + cc;

  int o0 = 0, o1 = 16384, o2 = 32768;   // ring byte offsets: t, t+1, t+2

  for (int t = 0; t < NT; t++) {
    const char* Ab = aA + o0;
    const char* Bb = aB + o0;

    // issue next-next tile's stages into ring slot o2 (bf16 offset = o2/2)
    if (t + 2 < NT) {
      SA(t + 2, 0, o2 >> 1); SA(t + 2, 1, o2 >> 1);
      SB(t + 2, 0, o2 >> 1); SB(t + 2, 1, o2 >> 1);
    }

    i32x4 av[4], bv[4];
#pragma unroll
    for (int n = 0; n < 4; n++) bv[n] = *(const i32x4*)(Bb + n * 1024);
#pragma unroll
    for (int m = 0; m < 4; m++) av[m] = *(const i32x4*)(Ab + m * 1024);
    __builtin_amdgcn_s_setprio(1);
#pragma unroll
    for (int m = 0; m < 4; m++)
#pragma unroll
      for (int n = 0; n < 4; n++)
        mfma16a(av[m], bv[n], acc[m][n]);
    __builtin_amdgcn_s_setprio(0);

    i32x4 av2[4];
#pragma unroll
    for (int m = 0; m < 4; m++) av2[m] = *(const i32x4*)(Ab + 4096 + m * 1024);
    __builtin_amdgcn_s_setprio(1);
#pragma unroll
    for (int m = 0; m < 4; m++)
#pragma unroll
      for (int n = 0; n < 4; n++)
        mfma16a(av2[m], bv[n], acc[4 + m][n]);
    __builtin_amdgcn_s_setprio(0);

    if (t + 2 < NT)      asm volatile("s_waitcnt vmcnt(4)" ::: "memory");
    else if (t + 1 < NT) asm volatile("s_waitcnt vmcnt(0)" ::: "memory");
    if (t + 1 < NT) BAR();

    int tmp = o0; o0 = o1; o1 = o2; o2 = tmp;   // rotate ring
  }
  asm volatile("s_waitcnt lgkmcnt(0)" ::: "memory");
  asm volatile("s_nop 7\n\ts_nop 7" ::);

  __bf16* Pp = nullptr;
  if (EPI == 3) {
    if (sk == 0)      Pp = (__bf16*)Cout;
    else if (sk == 1) Pp = (__bf16*)Cout2;
    else if (sk == 2) Pp = (__bf16*)Cout3;
    else              Pp = (__bf16*)Cout4;
  }

  int row0 = (bm << 8) + wr * 128;
  int col0 = (bn << 8) + wc * 64;
#pragma unroll
  for (int m = 0; m < 8; m++) {
#pragma unroll
    for (int n = 0; n < 4; n++) {
      int cc2 = col0 + n * 16 + lr;
      float bvv = (EPI == 3) ? 0.f : bias[cc2];
#pragma unroll
      for (int r = 0; r < 4; r++) {
        int row = row0 + m * 16 + (lg << 2) + r;
        float v = acc[m][n][r] + bvv;
        size_t idx = (size_t)row * N + cc2;
        if (EPI == 2) {
          float u = 0.7978845608028654f * (v + 0.044715f * v * v * v);
          u = fminf(fmaxf(u, -15.f), 15.f);
          float e = __expf(2.f * u);
          float th = (e - 1.f) / (e + 1.f);
          ((__bf16*)Cout)[idx] = (__bf16)(0.5f * v * (1.f + th));
        } else if (EPI == 4) {
          float scq = (cc2 < 1024) ? QSCALE : 1.f;
          ((__bf16*)Cout)[idx] = (__bf16)(v * scq);
        } else {
          Pp[idx] = (__bf16)v;
        }
      }
    }
  }
}

// =====================================================================
// W2 split-K(4) reduce, bf16 partials (4 scattered buffers):
//   Out = Out + gate[b,col] * (P0+P1+P2+P3 + bias[col])   (in place on Z)
// =====================================================================
__global__ __launch_bounds__(256)
void reduce_w2(const __bf16* __restrict__ P0, const __bf16* __restrict__ P1,
               const __bf16* __restrict__ P2, const __bf16* __restrict__ P3,
               const float* __restrict__ bias, const float* __restrict__ cproj,
               float* __restrict__ Out)
{
  int row = blockIdx.x;
  int b = row >> 10;
  int tid = threadIdx.x;
  size_t base = (size_t)row * D_ + tid * 4;
  bf16x4 a0 = *(const bf16x4*)(P0 + base);
  bf16x4 a1 = *(const bf16x4*)(P1 + base);
  bf16x4 a2 = *(const bf16x4*)(P2 + base);
  bf16x4 a3 = *(const bf16x4*)(P3 + base);
  f32x4 s;
#pragma unroll
  for (int i = 0; i < 4; i++)
    s[i] = ((float)a0[i] + (float)a1[i]) + ((float)a2[i] + (float)a3[i]);
  f32x4 bz = *(const f32x4*)(bias + tid * 4);
  f32x4 g  = *(const f32x4*)(cproj + b * SIXD + 5120 + tid * 4);
  f32x4 z  = *(const f32x4*)(Out + base);
  *(f32x4*)(Out + base) = z + g * (s + bz);
}

// =====================================================================
// flash attention, no-max softmax (Q pre-scaled so P = exp2(S)).
// 8 waves = 128 q rows of one (b,h); KVBLK=64, double-buffered staging.
// =====================================================================
__global__ __launch_bounds__(512, 4)
void attn_flash(const __bf16* __restrict__ qkv, const __bf16* __restrict__ Vt,
                __bf16* __restrict__ O)
{
  __shared__ __align__(16) __bf16 Kl[2][64 * 64];
  __shared__ __align__(16) __bf16 Vl[2][64 * 64];
  __shared__ __align__(16) __bf16 Pl[8][16 * 64];

  int bid = ((blockIdx.x & 7) << 6) | (blockIdx.x >> 3);  // XCD swizzle
  int qt = bid & 7, h = (bid >> 3) & 15, b = bid >> 7;
  int tid = threadIdx.x, wave = tid >> 6, lane = tid & 63;
  int lr = lane & 15, lg = lane >> 4;

  size_t tok0 = (size_t)b * 1024;
  int qrow = qt * 128 + wave * 16 + lr;
  const __bf16* qptr = qkv + (tok0 + qrow) * 3072 + h * 64;
  i32x4 qf0 = *(const i32x4*)(qptr + lg * 8);
  i32x4 qf1 = *(const i32x4*)(qptr + 32 + lg * 8);

  float l_acc[4] = {0.f, 0.f, 0.f, 0.f};
  f32x4 oacc[4] = {};

  const __bf16* kbase = qkv + tok0 * 3072 + 1024 + h * 64;
  const __bf16* vbase = Vt + ((size_t)(b * 16 + h) * 64) * 1024;

  int skey = tid >> 3, sdb = tid & 7;
  const __bf16* ksrc = kbase + (size_t)skey * 3072 + ((sdb ^ (skey & 7)) * 8);
  const __bf16* vsrc = vbase + (size_t)skey * 1024 + ((sdb ^ (skey & 7)) * 8);
  __bf16* klp = &Kl[0][0] + tid * 8;
  __bf16* vlp = &Vl[0][0] + tid * 8;
  __bf16* pl = &Pl[wave][0];

  auto STAGE = [&](int buf, int kk) {
    gload_lds16(ksrc + (size_t)kk * 3072, klp + buf * 4096);
    gload_lds16(vsrc + kk, vlp + buf * 4096);
  };

  STAGE(0, 0);
  int cur = 0;
  for (int k0 = 0; k0 < 1024; k0 += 64) {
    int kn = (k0 + 64 < 1024) ? (k0 + 64) : k0;
    STAGE(cur ^ 1, kn);
    asm volatile("s_waitcnt vmcnt(2)" ::: "memory");
    BAR();
    const __bf16* K_ = &Kl[cur][0];
    const __bf16* V_ = &Vl[cur][0];

    f32x4 s[4];
    __builtin_amdgcn_s_setprio(1);
#pragma unroll
    for (int n = 0; n < 4; n++) {
      int key = n * 16 + lr;
      int kx = key & 7;
      i32x4 kf0 = *(const i32x4*)(K_ + key * 64 + ((lg ^ kx) * 8));
      i32x4 kf1 = *(const i32x4*)(K_ + key * 64 + (((4 + lg) ^ kx) * 8));
      f32x4 sa = {0.f, 0.f, 0.f, 0.f};
      mfma16(qf0, kf0, sa);
      mfma16(qf1, kf1, sa);
      s[n] = sa;
    }
    __builtin_amdgcn_s_setprio(0);

#pragma unroll
    for (int n = 0; n < 4; n++)
#pragma unroll
      for (int r = 0; r < 4; r++)
        s[n][r] = exp2f(s[n][r]);
#pragma unroll
    for (int r = 0; r < 4; r++)
      l_acc[r] += (s[0][r] + s[1][r]) + (s[2][r] + s[3][r]);

#pragma unroll
    for (int n = 0; n < 4; n++)
#pragma unroll
      for (int r = 0; r < 4; r++) {
        int prow = lg * 4 + r;
        int key = n * 16 + lr;
        int idx = prow * 64 + (((key >> 3) ^ (prow & 7)) * 8) + (key & 7);
        pl[idx] = (__bf16)s[n][r];
      }
    asm volatile("s_waitcnt lgkmcnt(0)" ::: "memory");
    __builtin_amdgcn_sched_barrier(0);
    i32x4 pf0 = *(const i32x4*)(pl + lr * 64 + ((lg ^ (lr & 7)) * 8));
    i32x4 pf1 = *(const i32x4*)(pl + lr * 64 + (((4 + lg) ^ (lr & 7)) * 8));

    __builtin_amdgcn_s_setprio(1);
#pragma unroll
    for (int dt = 0; dt < 4; dt++) {
      int vrow = dt * 16 + lr, rx = vrow & 7;
      i32x4 vf0 = *(const i32x4*)(V_ + vrow * 64 + ((lg ^ rx) * 8));
      i32x4 vf1 = *(const i32x4*)(V_ + vrow * 64 + (((4 + lg) ^ rx) * 8));
      mfma16(pf0, vf0, oacc[dt]);
      mfma16(pf1, vf1, oacc[dt]);
    }
    __builtin_amdgcn_s_setprio(0);
    asm volatile("s_waitcnt lgkmcnt(0)" ::: "memory");
    __builtin_amdgcn_sched_barrier(0);
    BAR();
    cur ^= 1;
  }
  asm volatile("s_waitcnt vmcnt(0)" ::: "memory");
  asm volatile("s_nop 7\n\ts_nop 7" ::);

  float rinv[4];
#pragma unroll
  for (int r = 0; r < 4; r++) {
    float v = l_acc[r];
#pragma unroll
    for (int off = 1; off < 16; off <<= 1) v += __shfl_xor(v, off, 64);
    rinv[r] = 1.f / v;
  }

  int orow = qt * 128 + wave * 16 + (lg << 2);
#pragma unroll
  for (int dt = 0; dt < 4; dt++)
#pragma unroll
    for (int r = 0; r < 4; r++) {
      float v = oacc[dt][r] * rinv[r];
      O[(tok0 + orow + r) * 1024 + h * 64 + dt * 16 + lr] = (__bf16)v;
    }
}

// =====================================================================
// fused: self-gram(+Y) -> X' -> cross-gram -> Z -> LN+modulate -> znorm
// 4 rows per block. Writes Z (f32) and znorm (bf16); X' never stored.
// =====================================================================
__global__ __launch_bounds__(256)
void gram_fused(const float* __restrict__ X, const float* __restrict__ Y,
                const float* __restrict__ cls,
                const float* __restrict__ A_s, const float* __restrict__ B_s,
                const float* __restrict__ rms_s,
                const float* __restrict__ C_r, const float* __restrict__ D_r,
                const float* __restrict__ rms_c,
                const float* __restrict__ cproj,
                float* __restrict__ Z, __bf16* __restrict__ Znorm)
{
  __shared__ float xs[4][D_];
  __shared__ float tp[8][4][32];
  __shared__ float t1[4][32];
  __shared__ float red[4][4];
  __shared__ float red2[4][4][2];
  int row0 = blockIdx.x * 4;
  int b = row0 >> 10;
  int tid = threadIdx.x;
  int wv = tid >> 6;

  f32x4 cv = *(const f32x4*)(cls + (size_t)b * D_ + tid * 4);
  f32x4 yv[4];
#pragma unroll
  for (int rr = 0; rr < 4; rr++) {
    ((f32x4*)xs[rr])[tid] = *(const f32x4*)(X + (size_t)(row0 + rr) * D_ + tid * 4);
    yv[rr] = *(const f32x4*)(Y + (size_t)(row0 + rr) * D_ + tid * 4);
  }
  __syncthreads();

  // ---- stage 1: t1 = x @ A_s ----
  {
    int r = tid & 31, seg = tid >> 5;
    float a0 = 0.f, a1 = 0.f, a2 = 0.f, a3 = 0.f;
    const float* ap = A_s + r;
    for (int d = seg * 128; d < seg * 128 + 128; d++) {
      float w = ap[d * 32];
      a0 += xs[0][d] * w; a1 += xs[1][d] * w;
      a2 += xs[2][d] * w; a3 += xs[3][d] * w;
    }
    tp[seg][0][r] = a0; tp[seg][1][r] = a1; tp[seg][2][r] = a2; tp[seg][3][r] = a3;
  }
  __syncthreads();
  if (tid < 128) {
    int rr = tid >> 5, r = tid & 31;
    float sv = 0.f;
#pragma unroll
    for (int g = 0; g < 8; g++) sv += tp[g][rr][r];
    t1[rr][r] = sv;
  }
  __syncthreads();

  // ---- g = t1 @ B_s ; rms ; X' = scale*g*rs + Y ; pv = X' * cls ----
  f32x4 g[4] = {};
  for (int r = 0; r < 32; r++) {
    f32x4 bv = *(const f32x4*)(B_s + (size_t)r * D_ + tid * 4);
    g[0] += t1[0][r] * bv; g[1] += t1[1][r] * bv;
    g[2] += t1[2][r] * bv; g[3] += t1[3][r] * bv;
  }
  float ssl[4];
#pragma unroll
  for (int rr = 0; rr < 4; rr++)
    ssl[rr] = g[rr][0]*g[rr][0] + g[rr][1]*g[rr][1] + g[rr][2]*g[rr][2] + g[rr][3]*g[rr][3];
#pragma unroll
  for (int off = 1; off < 64; off <<= 1)
#pragma unroll
    for (int rr = 0; rr < 4; rr++) ssl[rr] += __shfl_xor(ssl[rr], off, 64);
  if ((tid & 63) == 0) {
#pragma unroll
    for (int rr = 0; rr < 4; rr++) red[wv][rr] = ssl[rr];
  }
  __syncthreads();
  {
    f32x4 scv = *(const f32x4*)(rms_s + tid * 4);
#pragma unroll
    for (int rr = 0; rr < 4; rr++) {
      float ss = red[0][rr] + red[1][rr] + red[2][rr] + red[3][rr];
      float rs = rsqrtf(ss * (1.f / D_) + 1e-6f);
      f32x4 xp = scv * g[rr] * rs + yv[rr];
      ((f32x4*)xs[rr])[tid] = xp * cv;
    }
  }
  __syncthreads();

  // ---- stage 2: t2 = (X'.cls) @ C_r ----
  {
    int r = tid & 31, seg = tid >> 5;
    float a0 = 0.f, a1 = 0.f, a2 = 0.f, a3 = 0.f;
    const float* cp = C_r + r;
    for (int d = seg * 128; d < seg * 128 + 128; d++) {
      float w = cp[d * 32];
      a0 += xs[0][d] * w; a1 += xs[1][d] * w;
      a2 += xs[2][d] * w; a3 += xs[3][d] * w;
    }
    tp[seg][0][r] = a0; tp[seg][1][r] = a1; tp[seg][2][r] = a2; tp[seg][3][r] = a3;
  }
  __syncthreads();
  if (tid < 128) {
    int rr = tid >> 5, r = tid & 31;
    float sv = 0.f;
#pragma unroll
    for (int g2i = 0; g2i < 8; g2i++) sv += tp[g2i][rr][r];
    t1[rr][r] = sv;
  }
  __syncthreads();

  // ---- g2 = t2 @ D_r ; rms -> z ----
  f32x4 g2[4] = {};
  for (int r = 0; r < 32; r++) {
    f32x4 bv = *(const f32x4*)(D_r + (size_t)r * D_ + tid * 4);
    g2[0] += t1[0][r] * bv; g2[1] += t1[1][r] * bv;
    g2[2] += t1[2][r] * bv; g2[3] += t1[3][r] * bv;
  }
#pragma unroll
  for (int rr = 0; rr < 4; rr++)
    ssl[rr] = g2[rr][0]*g2[rr][0] + g2[rr][1]*g2[rr][1] + g2[rr][2]*g2[rr][2] + g2[rr][3]*g2[rr][3];
#pragma unroll
  for (int off = 1; off < 64; off <<= 1)
#pragma unroll
    for (int rr = 0; rr < 4; rr++) ssl[rr] += __shfl_xor(ssl[rr], off, 64);
  if ((tid & 63) == 0) {
#pragma unroll
    for (int rr = 0; rr < 4; rr++) red[wv][rr] = ssl[rr];
  }
  __syncthreads();
  f32x4 z[4];
  {
    f32x4 scv = *(const f32x4*)(rms_c + tid * 4);
#pragma unroll
    for (int rr = 0; rr < 4; rr++) {
      float ss = red[0][rr] + red[1][rr] + red[2][rr] + red[3][rr];
      float rs = rsqrtf(ss * (1.f / D_) + 1e-6f);
      z[rr] = scv * g2[rr] * rs;
    }
  }

  // ---- LN + modulate of z -> znorm ----
  float s1l[4], s2l[4];
#pragma unroll
  for (int rr = 0; rr < 4; rr++) {
    s1l[rr] = z[rr][0] + z[rr][1] + z[rr][2] + z[rr][3];
    s2l[rr] = z[rr][0]*z[rr][0] + z[rr][1]*z[rr][1] + z[rr][2]*z[rr][2] + z[rr][3]*z[rr][3];
  }
#pragma unroll
  for (int off = 1; off < 64; off <<= 1)
#pragma unroll
    for (int rr = 0; rr < 4; rr++) {
      s1l[rr] += __shfl_xor(s1l[rr], off, 64);
      s2l[rr] += __shfl_xor(s2l[rr], off, 64);
    }
  if ((tid & 63) == 0) {
#pragma unroll
    for (int rr = 0; rr < 4; rr++) { red2[wv][rr][0] = s1l[rr]; red2[wv][rr][1] = s2l[rr]; }
  }
  __syncthreads();
  f32x4 shv = *(const f32x4*)(cproj + b * SIXD + 3072 + tid * 4);
  f32x4 scm = *(const f32x4*)(cproj + b * SIXD + 4096 + tid * 4);
#pragma unroll
  for (int rr = 0; rr < 4; rr++) {
    float S  = red2[0][rr][0] + red2[1][rr][0] + red2[2][rr][0] + red2[3][rr][0];
    float S2 = red2[0][rr][1] + red2[1][rr][1] + red2[2][rr][1] + red2[3][rr][1];
    float mean = S * (1.f / D_);
    float var  = S2 * (1.f / D_) - mean * mean;
    float rstd = rsqrtf(var + 1e-6f);
    f32x4 zn = (z[rr] - mean) * rstd * (scm + 1.f) + shv;
    *(f32x4*)(Z + (size_t)(row0 + rr) * D_ + tid * 4) = z[rr];
    bf16x4 o;
#pragma unroll
    for (int i = 0; i < 4; i++) o[i] = (__bf16)zn[i];
    *(bf16x4*)(Znorm + (size_t)(row0 + rr) * D_ + tid * 4) = o;
  }
}

// =====================================================================
extern "C" void kernel_launch(void* const* d_in, const int* in_sizes, int n_in,
                              void* d_out, int out_size, void* d_ws, size_t ws_size,
                              hipStream_t stream)
{
  const float* x     = (const float*)d_in[0];
  const float* c     = (const float*)d_in[1];
  const float* cls   = (const float*)d_in[2];
  const float* Wc    = (const float*)d_in[3];
  const float* bc    = (const float*)d_in[4];
  const float* Wqkv  = (const float*)d_in[5];
  const float* bqkv  = (const float*)d_in[6];
  const float* Wo    = (const float*)d_in[7];
  const float* bo    = (const float*)d_in[8];
  const float* A_s   = (const float*)d_in[9];
  const float* B_s   = (const float*)d_in[10];
  const float* rms_s = (const float*)d_in[11];
  const float* C_r   = (const float*)d_in[12];
  const float* D_r   = (const float*)d_in[13];
  const float* rms_c = (const float*)d_in[14];
  const float* W1    = (const float*)d_in[15];
  const float* b1    = (const float*)d_in[16];
  const float* W2    = (const float*)d_in[17];
  const float* b2    = (const float*)d_in[18];
  float* out = (float*)d_out;

  float* ws = (float*)d_ws;
  __bf16* Wqkvt = (__bf16*)(ws + 0);         // 3072x1024 bf16  [floats 0..1572864)
  __bf16* Wot   = (__bf16*)(ws + 1572864);   // 1024x1024       [..2097152)
  __bf16* W1t   = (__bf16*)(ws + 2097152);   // 4096x1024       [..4194304)
  __bf16* W2t   = (__bf16*)(ws + 4194304);   // 1024x4096       [..6291456)
  float*  cproj = ws + 6291456;              // 4x6144          [..6316032)
  __bf16* xnorm = (__bf16*)(ws + 6316032);   // 4096x1024 (also znorm)  [..8413184)
  __bf16* qkv   = (__bf16*)(ws + 8413184);   // 4096x3072       [..14704640)
  __bf16* Vt    = (__bf16*)(ws + 14704640);  // 64x64x1024      [..16801792)
  __bf16* h1    = (__bf16*)(ws + 8413184);   // 4096x4096 (reuses qkv+Vt)
  __bf16* attno = (__bf16*)(ws + 16801792);  // 4096x1024       [..18898944)
  float*  Ybuf  = ws + 18898944;             // 4096x1024 f32 (Y)  [..20996096)
  // W2 split-K(4) bf16 partials, 8 MB each, in regions dead at W2-GEMM time.
  // W2t [4194304..6291456) and h1 [8413184..16801792) are NOT touched.
  __bf16* P0 = (__bf16*)(ws + 0);            // over Wqkvt+Wot (dead)
  __bf16* P1 = (__bf16*)(ws + 2097152);      // over W1t (dead after W1 GEMM)
  __bf16* P2 = (__bf16*)(ws + 16801792);     // over attno (dead after Wo GEMM)
  __bf16* P3 = (__bf16*)(ws + 18898944);     // over Ybuf (dead after gram_fused)

  prep<<<3264, 256, 0, stream>>>(c, Wc, bc, cproj,
                                 Wqkv, Wo, W1, W2, Wqkvt, Wot, W1t, W2t);
  ln_mod<<<4096, 256, 0, stream>>>(x, cproj, 0, 1024, xnorm);
  gemm256<4, 32, 1024><<<192, 512, 0, stream>>>(xnorm, Wqkvt, bqkv,
                                                qkv, nullptr, nullptr, nullptr,
                                                4096, 3072);
  transpose_v<<<4096, 256, 0, stream>>>(qkv, Vt);
  attn_flash<<<512, 512, 0, stream>>>(qkv, Vt, attno);
  gemm_bt<1, 4><<<256, 256, 0, stream>>>(attno, Wot, bo, cproj, 2048, x,
                                         Ybuf, nullptr, nullptr, nullptr,
                                         4096, 1024, 1024, 1);
  gram_fused<<<1024, 256, 0, stream>>>(x, Ybuf, cls, A_s, B_s, rms_s,
                                       C_r, D_r, rms_c, cproj, out, xnorm);
  gemm256<2, 32, 1024><<<256, 512, 0, stream>>>(xnorm, W1t, b1,
                                                h1, nullptr, nullptr, nullptr,
                                                4096, 4096);
  gemm256<3, 32, 4096><<<256, 512, 0, stream>>>(h1, W2t, nullptr,
                                                P0, P1, P2, P3, 4096, 1024);
  reduce_w2<<<4096, 256, 0, stream>>>(P0, P1, P2, P3, b2, cproj, out);
}

// Round 6
// 256.498 us; speedup vs baseline: 1.3154x; 1.1264x over previous
//
#include <hip/hip_runtime.h>
#include <stdint.h>

typedef float  f32x4  __attribute__((ext_vector_type(4)));
typedef short  s16x8  __attribute__((ext_vector_type(8)));   // 8 bf16 (4 VGPRs)
typedef __bf16 bf16x4 __attribute__((ext_vector_type(4)));

#define D_    1024
#define SIXD  6144
// 0.125 (1/sqrt(64)) * log2(e): folded into Q so attn P = exp2(S) directly
#define QSCALE 0.18033688011112042f

#define BAR() asm volatile("s_barrier" ::: "memory")

// builtin MFMA: compiler owns acc registers + per-use counted lgkmcnt waits
__device__ __forceinline__ f32x4 mfma_b(const s16x8 &a, const s16x8 &b, const f32x4 &c) {
  return __builtin_amdgcn_mfma_f32_16x16x32_bf16(a, b, c, 0, 0, 0);
}

__device__ __forceinline__ void gload_lds16(const void* g, void* l) {
  __builtin_amdgcn_global_load_lds(
      (const __attribute__((address_space(1))) uint32_t*)g,
      (__attribute__((address_space(3))) uint32_t*)l, 16, 0, 0);
}

// =====================================================================
// prep: fused cond_gemm (blocks 0..191) + weight transposes (192..3263)
//  cond: cproj[b,:] = silu(c[b,:]) @ Wc + bc
//  transpose: fp32 W -> bf16 W^T, 64x64 tiles
// =====================================================================
__global__ __launch_bounds__(256)
void prep(const float* __restrict__ c, const float* __restrict__ Wc,
          const float* __restrict__ bc, float* __restrict__ cproj,
          const float* __restrict__ Wqkv, const float* __restrict__ Wo,
          const float* __restrict__ W1, const float* __restrict__ W2,
          __bf16* __restrict__ Wqkvt, __bf16* __restrict__ Wot,
          __bf16* __restrict__ W1t, __bf16* __restrict__ W2t)
{
  __shared__ float sc[4096];
  __shared__ float tp[8][4][32];
  __shared__ __bf16 tt[64][65];
  int tid = threadIdx.x;
  if (blockIdx.x < 192) {
    for (int i = tid; i < 4096; i += 256) {
      float v = c[i];
      sc[i] = v / (1.f + __expf(-v));
    }
    __syncthreads();
    int colo = tid & 31, kseg = tid >> 5;
    int col = blockIdx.x * 32 + colo;
    float a0 = 0.f, a1 = 0.f, a2 = 0.f, a3 = 0.f;
    for (int k = kseg * 128; k < kseg * 128 + 128; k++) {
      float w = Wc[(size_t)k * SIXD + col];
      a0 += sc[k] * w; a1 += sc[1024 + k] * w;
      a2 += sc[2048 + k] * w; a3 += sc[3072 + k] * w;
    }
    tp[kseg][0][colo] = a0; tp[kseg][1][colo] = a1;
    tp[kseg][2][colo] = a2; tp[kseg][3][colo] = a3;
    __syncthreads();
    if (kseg == 0) {
#pragma unroll
      for (int b = 0; b < 4; b++) {
        float s = bc[col];
#pragma unroll
        for (int g = 0; g < 8; g++) s += tp[g][b][colo];
        cproj[b * SIXD + col] = s;
      }
    }
    return;
  }
  int bid = blockIdx.x - 192;
  const float* W; __bf16* Wt; int Kdim, Ndim, lb;
  if (bid < 768)       { W = Wqkv; Wt = Wqkvt; Kdim = 1024; Ndim = 3072; lb = bid; }
  else if (bid < 1024) { W = Wo;   Wt = Wot;   Kdim = 1024; Ndim = 1024; lb = bid - 768; }
  else if (bid < 2048) { W = W1;   Wt = W1t;   Kdim = 1024; Ndim = 4096; lb = bid - 1024; }
  else                 { W = W2;   Wt = W2t;   Kdim = 4096; Ndim = 1024; lb = bid - 2048; }
  int ntn = Ndim >> 6;
  int kt = lb / ntn, nt = lb % ntn;
  const float* src = W + (size_t)(kt * 64) * Ndim + nt * 64;
#pragma unroll
  for (int i = 0; i < 4; i++) {
    int k = i * 16 + (tid >> 4);
    int c4 = tid & 15;
    float4 v = ((const float4*)(src + (size_t)k * Ndim))[c4];
    tt[k][c4 * 4 + 0] = (__bf16)v.x; tt[k][c4 * 4 + 1] = (__bf16)v.y;
    tt[k][c4 * 4 + 2] = (__bf16)v.z; tt[k][c4 * 4 + 3] = (__bf16)v.w;
  }
  __syncthreads();
  __bf16* dst = Wt + (size_t)(nt * 64) * Kdim + kt * 64;
  int n = tid >> 2, ks = (tid & 3) * 16;
  bf16x4 o0, o1, o2, o3;
#pragma unroll
  for (int j = 0; j < 4; j++) {
    o0[j] = tt[ks + j][n];      o1[j] = tt[ks + 4 + j][n];
    o2[j] = tt[ks + 8 + j][n];  o3[j] = tt[ks + 12 + j][n];
  }
  __bf16* dp = dst + (size_t)n * Kdim + ks;
  *(bf16x4*)(dp) = o0; *(bf16x4*)(dp + 4) = o1;
  *(bf16x4*)(dp + 8) = o2; *(bf16x4*)(dp + 12) = o3;
}

// =====================================================================
// V-part of qkv (bf16) -> Vt[(b*16+h)*64 + d][n]
// =====================================================================
__global__ __launch_bounds__(256)
void transpose_v(const __bf16* __restrict__ qkv, __bf16* __restrict__ Vt)
{
  __shared__ __bf16 t[32][33];
  int bid = blockIdx.x;
  int dt = bid & 1, nt = (bid >> 1) & 31, bh = bid >> 6;
  int b = bh >> 4, h = bh & 15;
  int x = threadIdx.x & 31, yq = threadIdx.x >> 5;
  const __bf16* src = qkv + ((size_t)(b * 1024 + nt * 32)) * 3072 + 2048 + h * 64 + dt * 32;
#pragma unroll
  for (int i = 0; i < 4; i++) {
    int row = yq * 4 + i;
    t[row][x] = src[(size_t)row * 3072 + x];
  }
  __syncthreads();
  __bf16* dst = Vt + ((size_t)(bh * 64 + dt * 32)) * 1024 + nt * 32;
#pragma unroll
  for (int i = 0; i < 4; i++) {
    int drow = yq * 4 + i;
    dst[(size_t)drow * 1024 + x] = t[x][drow];
  }
}

// =====================================================================
// fused LayerNorm + modulate, fp32 in -> bf16 out
// =====================================================================
__global__ __launch_bounds__(256)
void ln_mod(const float* __restrict__ X, const float* __restrict__ cproj,
            int shift_off, int scale_off, __bf16* __restrict__ Out)
{
  int row = blockIdx.x;
  int b = row >> 10;
  int tid = threadIdx.x;
  const float4* xr = (const float4*)(X + (size_t)row * D_);
  float4 v = xr[tid];
  float s  = v.x + v.y + v.z + v.w;
  float s2 = v.x * v.x + v.y * v.y + v.z * v.z + v.w * v.w;
#pragma unroll
  for (int off = 1; off < 64; off <<= 1) {
    s  += __shfl_xor(s,  off, 64);
    s2 += __shfl_xor(s2, off, 64);
  }
  __shared__ float red[8];
  int wave = tid >> 6, lane = tid & 63;
  if (lane == 0) { red[wave] = s; red[4 + wave] = s2; }
  __syncthreads();
  s  = red[0] + red[1] + red[2] + red[3];
  s2 = red[4] + red[5] + red[6] + red[7];
  float mean = s * (1.f / D_);
  float var  = s2 * (1.f / D_) - mean * mean;
  float rstd = rsqrtf(var + 1e-6f);
  const float4* sh = (const float4*)(cproj + b * SIXD + shift_off);
  const float4* sc = (const float4*)(cproj + b * SIXD + scale_off);
  float4 shv = sh[tid], scv = sc[tid];
  bf16x4 o;
  o[0] = (__bf16)((v.x - mean) * rstd * (1.f + scv.x) + shv.x);
  o[1] = (__bf16)((v.y - mean) * rstd * (1.f + scv.y) + shv.y);
  o[2] = (__bf16)((v.z - mean) * rstd * (1.f + scv.z) + shv.z);
  o[3] = (__bf16)((v.w - mean) * rstd * (1.f + scv.w) + shv.w);
  *(bf16x4*)(Out + (size_t)row * D_ + tid * 4) = o;
}

// =====================================================================
// bf16 MFMA GEMM, C = A(MxK) @ Bt(NxK)^T, 128x128 tile, BK=32.
// NBUF-deep LDS pipeline, XCD-swizzled grid. (Used for Wo: N=1024)
// EPI 1: f32 = resid + gate * (acc + bias)
// =====================================================================
template<int EPI, int NBUF>
__global__ __launch_bounds__(256)
void gemm_bt(const __bf16* __restrict__ A, const __bf16* __restrict__ Bt,
             const float* __restrict__ bias, const float* __restrict__ cproj,
             int gate_off, const float* __restrict__ resid,
             void* __restrict__ Cout, void* __restrict__ Cout2,
             void* __restrict__ Cout3, void* __restrict__ Cout4,
             int M, int N, int K, int SK)
{
  __shared__ __align__(16) __bf16 As[NBUF * 128 * 32];
  __shared__ __align__(16) __bf16 Bs[NBUF * 128 * 32];
  const int PD = NBUF - 1;
  int tilesN = N >> 7, tilesM = M >> 7;
  int npersk = tilesM * tilesN;
  int sk = blockIdx.x / npersk;
  int rest = blockIdx.x % npersk;
  int cpx = npersk >> 3;
  rest = (rest & 7) * cpx + (rest >> 3);   // XCD-contiguous chunks
  int bm = rest / tilesN, bn = rest % tilesN;
  int Klen = K / SK, Kstart = sk * Klen;

  int tid = threadIdx.x;
  int lane = tid & 63, wave = tid >> 6;
  int lr = lane & 15, lg = lane >> 4;
  int wm = (wave >> 1) << 6, wn = (wave & 1) << 6;

  f32x4 acc[4][4] = {};

  int sr = tid >> 2, skb = tid & 3;
  int scol = ((skb ^ ((sr >> 1) & 3)) * 8);
  const __bf16* pa = A + (size_t)((bm << 7) + sr) * K + Kstart + scol;
  const __bf16* pb = Bt + (size_t)((bn << 7) + sr) * K + Kstart + scol;
  const size_t rstep = (size_t)64 * K;
  __bf16* la = As + tid * 8;
  __bf16* lb = Bs + tid * 8;

  auto STAGE = [&](int buf, int k0) {
    int bo = buf * 4096;
    gload_lds16(pa + k0, la + bo);
    gload_lds16(pa + rstep + k0, la + bo + 2048);
    gload_lds16(pb + k0, lb + bo);
    gload_lds16(pb + rstep + k0, lb + bo + 2048);
  };

  int nt = Klen >> 5;
#pragma unroll
  for (int p = 0; p < PD; p++) STAGE(p, p * 32);

  for (int t = 0; t < nt; t++) {
    if (t + PD < nt) STAGE((t + PD) % NBUF, (t + PD) * 32);
    int ahead = nt - 1 - t; if (ahead > PD) ahead = PD;
    if (ahead >= 3)      asm volatile("s_waitcnt vmcnt(12)" ::: "memory");
    else if (ahead == 2) asm volatile("s_waitcnt vmcnt(8)" ::: "memory");
    else if (ahead == 1) asm volatile("s_waitcnt vmcnt(4)" ::: "memory");
    else                 asm volatile("s_waitcnt vmcnt(0)" ::: "memory");
    BAR();
    const __bf16* Ac = As + (t % NBUF) * 4096;
    const __bf16* Bc = Bs + (t % NBUF) * 4096;
    s16x8 af[4], bfv[4];
#pragma unroll
    for (int m = 0; m < 4; m++) {
      int row = wm + m * 16 + lr;
      af[m] = *(const s16x8*)(Ac + row * 32 + ((lg ^ ((row >> 1) & 3)) * 8));
    }
#pragma unroll
    for (int n = 0; n < 4; n++) {
      int row = wn + n * 16 + lr;
      bfv[n] = *(const s16x8*)(Bc + row * 32 + ((lg ^ ((row >> 1) & 3)) * 8));
    }
    asm volatile("s_waitcnt lgkmcnt(0)" ::: "memory");
    __builtin_amdgcn_sched_barrier(0);
    BAR();
    __builtin_amdgcn_s_setprio(1);
#pragma unroll
    for (int m = 0; m < 4; m++)
#pragma unroll
      for (int n = 0; n < 4; n++)
        acc[m][n] = mfma_b(af[m], bfv[n], acc[m][n]);
    __builtin_amdgcn_s_setprio(0);
  }
  asm volatile("s_waitcnt vmcnt(0)" ::: "memory");

  __bf16* Pp = nullptr;
  if (EPI == 3) {
    if (sk == 0)      Pp = (__bf16*)Cout;
    else if (sk == 1) Pp = (__bf16*)Cout2;
    else if (sk == 2) Pp = (__bf16*)Cout3;
    else              Pp = (__bf16*)Cout4;
  }

  int row0 = (bm << 7) + wm;
  int col0 = (bn << 7) + wn;
#pragma unroll
  for (int m = 0; m < 4; m++) {
#pragma unroll
    for (int n = 0; n < 4; n++) {
      int cc = col0 + n * 16 + lr;
      float bv = (EPI == 3) ? 0.f : bias[cc];
#pragma unroll
      for (int r = 0; r < 4; r++) {
        int row = row0 + m * 16 + (lg << 2) + r;
        float v = acc[m][n][r] + bv;
        size_t idx = (size_t)row * N + cc;
        if (EPI == 0) {
          ((__bf16*)Cout)[idx] = (__bf16)v;
        } else if (EPI == 1) {
          int b = row >> 10;
          float g = cproj[b * SIXD + gate_off + cc];
          ((float*)Cout)[idx] = resid[idx] + g * v;
        } else if (EPI == 2) {
          float u = 0.7978845608028654f * (v + 0.044715f * v * v * v);
          u = fminf(fmaxf(u, -15.f), 15.f);
          float e = __expf(2.f * u);
          float th = (e - 1.f) / (e + 1.f);
          ((__bf16*)Cout)[idx] = (__bf16)(0.5f * v * (1.f + th));
        } else if (EPI == 4) {
          float scq = (cc < 1024) ? QSCALE : 1.f;
          ((__bf16*)Cout)[idx] = (__bf16)(v * scq);
        } else {
          Pp[idx] = (__bf16)v;
        }
      }
    }
  }
}

// =====================================================================
// 256x256-tile deep-pipelined 3-phase bf16 MFMA GEMM (r3 schedule,
// builtin MFMA). BK=64, 8 waves (2M x 4N), 512 threads, 128 KiB LDS.
// Per wave: 128x64 output, acc[8][4] f32x4 (compiler-allocated).
//  P1: read b1(t);  MFMA Q1(alo x b0);             lgkm0; BAR  (b1 drained)
//  P2: read ahi(t); SB(t+2,q0,q1); MFMA Q2(alo x b1); lgkm0; BAR (ahi drained)
//  P3: SB(t+2,q2,q3)+SA(t+2,q0-q3); MFMA Q3+Q4 (32);
//      vmcnt(8) [only t+2's 8 left -> t+1 landed]; BAR;
//      pre-read alo(t+1), b0(t+1)
// EPI 2: bf16 = gelu_tanh(acc + bias)
// EPI 3: bf16 partial = acc -> Pk[sk]
// EPI 4: bf16 = (acc + bias) * (col<1024 ? QSCALE : 1)
// =====================================================================
template<int EPI, int NT, int KD>
__global__ __launch_bounds__(512, 2)
void gemm256(const __bf16* __restrict__ A, const __bf16* __restrict__ Bt,
             const float* __restrict__ bias,
             void* __restrict__ Cout, void* __restrict__ Cout2,
             void* __restrict__ Cout3, void* __restrict__ Cout4,
             int M, int N)
{
  __shared__ __align__(16) __bf16 As[2 * 16384];   // 2 x 256x64
  __shared__ __align__(16) __bf16 Bs[2 * 16384];
  int tilesN = N >> 8, tilesM = M >> 8;
  int npersk = tilesM * tilesN;
  int sk = blockIdx.x / npersk;
  int rest = blockIdx.x % npersk;
  int cpx = npersk >> 3;
  rest = (rest & 7) * cpx + (rest >> 3);   // XCD-contiguous chunks
  int bm = rest / tilesN, bn = rest % tilesN;
  int Kstart = sk * (NT * 64);

  int tid = threadIdx.x;
  int lane = tid & 63, wave = tid >> 6;
  int lr = lane & 15, lg = lane >> 4;
  int wr = wave >> 2, wc = wave & 3;

  f32x4 acc[8][4] = {};

  // staging: one gload covers 64 rows x 64 k; thread -> (row=tid>>3, chunk)
  int srow = tid >> 3;
  int schunk = (tid & 7) ^ (srow & 7);     // pre-swizzled global source
  const __bf16* pa = A  + (size_t)((bm << 8) + srow) * KD + Kstart + schunk * 8;
  const __bf16* pb = Bt + (size_t)((bn << 8) + srow) * KD + Kstart + schunk * 8;
  __bf16* la = As + tid * 8;
  __bf16* lb = Bs + tid * 8;

  // quarter q (64 rows) of tile t
  auto SAq = [&](int t, int q) {
    gload_lds16(pa + (size_t)(q * 64) * KD + t * 64,
                la + (t & 1) * 16384 + q * 4096);
  };
  auto SBq = [&](int t, int q) {
    gload_lds16(pb + (size_t)(q * 64) * KD + t * 64,
                lb + (t & 1) * 16384 + q * 4096);
  };

  // prologue: A(0),B(0) then A(1),B(1)
#pragma unroll
  for (int q = 0; q < 4; q++) { SAq(0, q); }
#pragma unroll
  for (int q = 0; q < 4; q++) { SBq(0, q); }
#pragma unroll
  for (int q = 0; q < 4; q++) { SAq(1, q); }
#pragma unroll
  for (int q = 0; q < 4; q++) { SBq(1, q); }
  asm volatile("s_waitcnt vmcnt(8)" ::: "memory");  // A(0),B(0) landed
  BAR();

  // ds_read addressing: row*128B + ((kchunk ^ (row&7))*16); row&7 == lr&7
  int cc0 = ((lg ^ (lr & 7)) << 4);
  int cc1 = cc0 ^ 64;
  const char* aA = (const char*)As + (wr * 128 + lr) * 128;
  const char* aB = (const char*)Bs + (wc * 64 + lr) * 128;

  s16x8 alo[4][2], ahi[4][2], b0v[2][2], b1v[2][2];
  // pre-read frags needed by Q1(0)
#pragma unroll
  for (int m = 0; m < 4; m++) {
    alo[m][0] = *(const s16x8*)(aA + m * 2048 + cc0);
    alo[m][1] = *(const s16x8*)(aA + m * 2048 + cc1);
  }
#pragma unroll
  for (int n = 0; n < 2; n++) {
    b0v[n][0] = *(const s16x8*)(aB + n * 2048 + cc0);
    b0v[n][1] = *(const s16x8*)(aB + n * 2048 + cc1);
  }

  for (int t = 0; t < NT; t++) {
    const char* Ab = aA + (t & 1) * 32768;
    const char* Bb = aB + (t & 1) * 32768;

    // ---------- P1: read b1(t); Q1 = alo x b0
#pragma unroll
    for (int n = 0; n < 2; n++) {
      b1v[n][0] = *(const s16x8*)(Bb + 4096 + n * 2048 + cc0);
      b1v[n][1] = *(const s16x8*)(Bb + 4096 + n * 2048 + cc1);
    }
    __builtin_amdgcn_sched_barrier(0);
    __builtin_amdgcn_s_setprio(1);
#pragma unroll
    for (int m = 0; m < 4; m++)
#pragma unroll
      for (int n = 0; n < 2; n++) {
        acc[m][n] = mfma_b(alo[m][0], b0v[n][0], acc[m][n]);
        acc[m][n] = mfma_b(alo[m][1], b0v[n][1], acc[m][n]);
      }
    __builtin_amdgcn_s_setprio(0);
    asm volatile("s_waitcnt lgkmcnt(0)" ::: "memory");  // b1(t) drained
    BAR();

    // ---------- P2: read ahi(t); stage B(t+2) q0,q1; Q2 = alo x b1
#pragma unroll
    for (int m = 0; m < 4; m++) {
      ahi[m][0] = *(const s16x8*)(Ab + 8192 + m * 2048 + cc0);
      ahi[m][1] = *(const s16x8*)(Ab + 8192 + m * 2048 + cc1);
    }
    if (t + 2 < NT) { SBq(t + 2, 0); SBq(t + 2, 1); }
    __builtin_amdgcn_sched_barrier(0);
    __builtin_amdgcn_s_setprio(1);
#pragma unroll
    for (int m = 0; m < 4; m++)
#pragma unroll
      for (int n = 0; n < 2; n++) {
        acc[m][2 + n] = mfma_b(alo[m][0], b1v[n][0], acc[m][2 + n]);
        acc[m][2 + n] = mfma_b(alo[m][1], b1v[n][1], acc[m][2 + n]);
      }
    __builtin_amdgcn_s_setprio(0);
    asm volatile("s_waitcnt lgkmcnt(0)" ::: "memory");  // ahi(t) drained
    BAR();

    // ---------- P3: stage B(t+2) q2,q3 + A(t+2) q0-q3; Q3+Q4; vmcnt; BAR
    if (t + 2 < NT) {
      SBq(t + 2, 2); SBq(t + 2, 3);
      SAq(t + 2, 0); SAq(t + 2, 1); SAq(t + 2, 2); SAq(t + 2, 3);
    }
    __builtin_amdgcn_sched_barrier(0);
    __builtin_amdgcn_s_setprio(1);
#pragma unroll
    for (int m = 0; m < 4; m++)
#pragma unroll
      for (int n = 0; n < 2; n++) {
        acc[4 + m][2 + n] = mfma_b(ahi[m][0], b1v[n][0], acc[4 + m][2 + n]);
        acc[4 + m][2 + n] = mfma_b(ahi[m][1], b1v[n][1], acc[4 + m][2 + n]);
      }
#pragma unroll
    for (int m = 0; m < 4; m++)
#pragma unroll
      for (int n = 0; n < 2; n++) {
        acc[4 + m][n] = mfma_b(ahi[m][0], b0v[n][0], acc[4 + m][n]);
        acc[4 + m][n] = mfma_b(ahi[m][1], b0v[n][1], acc[4 + m][n]);
      }
    __builtin_amdgcn_s_setprio(0);
    if (t + 1 < NT) {
      if (t + 2 < NT) asm volatile("s_waitcnt vmcnt(8)" ::: "memory");
      else            asm volatile("s_waitcnt vmcnt(0)" ::: "memory");
      BAR();   // all waves: A(t+1),B(t+1) fully landed
      const char* An = aA + ((t + 1) & 1) * 32768;
      const char* Bn = aB + ((t + 1) & 1) * 32768;
#pragma unroll
      for (int m = 0; m < 4; m++) {
        alo[m][0] = *(const s16x8*)(An + m * 2048 + cc0);
        alo[m][1] = *(const s16x8*)(An + m * 2048 + cc1);
      }
#pragma unroll
      for (int n = 0; n < 2; n++) {
        b0v[n][0] = *(const s16x8*)(Bn + n * 2048 + cc0);
        b0v[n][1] = *(const s16x8*)(Bn + n * 2048 + cc1);
      }
    }
  }
  asm volatile("s_waitcnt lgkmcnt(0)" ::: "memory");

  __bf16* Pp = nullptr;
  if (EPI == 3) {
    if (sk == 0)      Pp = (__bf16*)Cout;
    else if (sk == 1) Pp = (__bf16*)Cout2;
    else if (sk == 2) Pp = (__bf16*)Cout3;
    else              Pp = (__bf16*)Cout4;
  }

  int row0 = (bm << 8) + wr * 128;
  int col0 = (bn << 8) + wc * 64;
#pragma unroll
  for (int m = 0; m < 8; m++) {
#pragma unroll
    for (int n = 0; n < 4; n++) {
      int cc = col0 + n * 16 + lr;
      float bv = (EPI == 3) ? 0.f : bias[cc];
#pragma unroll
      for (int r = 0; r < 4; r++) {
        int row = row0 + m * 16 + (lg << 2) + r;
        float v = acc[m][n][r] + bv;
        size_t idx = (size_t)row * N + cc;
        if (EPI == 2) {
          float u = 0.7978845608028654f * (v + 0.044715f * v * v * v);
          u = fminf(fmaxf(u, -15.f), 15.f);
          float e = __expf(2.f * u);
          float th = (e - 1.f) / (e + 1.f);
          ((__bf16*)Cout)[idx] = (__bf16)(0.5f * v * (1.f + th));
        } else if (EPI == 4) {
          float scq = (cc < 1024) ? QSCALE : 1.f;
          ((__bf16*)Cout)[idx] = (__bf16)(v * scq);
        } else {
          Pp[idx] = (__bf16)v;
        }
      }
    }
  }
}

// =====================================================================
// W2 split-K(4) reduce, bf16 partials (4 scattered buffers):
//   Out = Out + gate[b,col] * (P0+P1+P2+P3 + bias[col])   (in place on Z)
// =====================================================================
__global__ __launch_bounds__(256)
void reduce_w2(const __bf16* __restrict__ P0, const __bf16* __restrict__ P1,
               const __bf16* __restrict__ P2, const __bf16* __restrict__ P3,
               const float* __restrict__ bias, const float* __restrict__ cproj,
               float* __restrict__ Out)
{
  int row = blockIdx.x;
  int b = row >> 10;
  int tid = threadIdx.x;
  size_t base = (size_t)row * D_ + tid * 4;
  bf16x4 a0 = *(const bf16x4*)(P0 + base);
  bf16x4 a1 = *(const bf16x4*)(P1 + base);
  bf16x4 a2 = *(const bf16x4*)(P2 + base);
  bf16x4 a3 = *(const bf16x4*)(P3 + base);
  f32x4 s;
#pragma unroll
  for (int i = 0; i < 4; i++)
    s[i] = ((float)a0[i] + (float)a1[i]) + ((float)a2[i] + (float)a3[i]);
  f32x4 bz = *(const f32x4*)(bias + tid * 4);
  f32x4 g  = *(const f32x4*)(cproj + b * SIXD + 5120 + tid * 4);
  f32x4 z  = *(const f32x4*)(Out + base);
  *(f32x4*)(Out + base) = z + g * (s + bz);
}

// =====================================================================
// flash attention, no-max softmax (Q pre-scaled so P = exp2(S)).
// 8 waves = 128 q rows of one (b,h); KVBLK=64, double-buffered staging.
// =====================================================================
__global__ __launch_bounds__(512, 4)
void attn_flash(const __bf16* __restrict__ qkv, const __bf16* __restrict__ Vt,
                __bf16* __restrict__ O)
{
  __shared__ __align__(16) __bf16 Kl[2][64 * 64];
  __shared__ __align__(16) __bf16 Vl[2][64 * 64];
  __shared__ __align__(16) __bf16 Pl[8][16 * 64];

  int bid = ((blockIdx.x & 7) << 6) | (blockIdx.x >> 3);  // XCD swizzle
  int qt = bid & 7, h = (bid >> 3) & 15, b = bid >> 7;
  int tid = threadIdx.x, wave = tid >> 6, lane = tid & 63;
  int lr = lane & 15, lg = lane >> 4;

  size_t tok0 = (size_t)b * 1024;
  int qrow = qt * 128 + wave * 16 + lr;
  const __bf16* qptr = qkv + (tok0 + qrow) * 3072 + h * 64;
  s16x8 qf0 = *(const s16x8*)(qptr + lg * 8);
  s16x8 qf1 = *(const s16x8*)(qptr + 32 + lg * 8);

  float l_acc[4] = {0.f, 0.f, 0.f, 0.f};
  f32x4 oacc[4] = {};

  const __bf16* kbase = qkv + tok0 * 3072 + 1024 + h * 64;
  const __bf16* vbase = Vt + ((size_t)(b * 16 + h) * 64) * 1024;

  int skey = tid >> 3, sdb = tid & 7;
  const __bf16* ksrc = kbase + (size_t)skey * 3072 + ((sdb ^ (skey & 7)) * 8);
  const __bf16* vsrc = vbase + (size_t)skey * 1024 + ((sdb ^ (skey & 7)) * 8);
  __bf16* klp = &Kl[0][0] + tid * 8;
  __bf16* vlp = &Vl[0][0] + tid * 8;
  __bf16* pl = &Pl[wave][0];

  auto STAGE = [&](int buf, int kk) {
    gload_lds16(ksrc + (size_t)kk * 3072, klp + buf * 4096);
    gload_lds16(vsrc + kk, vlp + buf * 4096);
  };

  STAGE(0, 0);
  int cur = 0;
  for (int k0 = 0; k0 < 1024; k0 += 64) {
    int kn = (k0 + 64 < 1024) ? (k0 + 64) : k0;
    STAGE(cur ^ 1, kn);
    asm volatile("s_waitcnt vmcnt(2)" ::: "memory");
    BAR();
    const __bf16* K_ = &Kl[cur][0];
    const __bf16* V_ = &Vl[cur][0];

    f32x4 s[4];
    __builtin_amdgcn_s_setprio(1);
#pragma unroll
    for (int n = 0; n < 4; n++) {
      int key = n * 16 + lr;
      int kx = key & 7;
      s16x8 kf0 = *(const s16x8*)(K_ + key * 64 + ((lg ^ kx) * 8));
      s16x8 kf1 = *(const s16x8*)(K_ + key * 64 + (((4 + lg) ^ kx) * 8));
      f32x4 sa = {0.f, 0.f, 0.f, 0.f};
      sa = mfma_b(qf0, kf0, sa);
      sa = mfma_b(qf1, kf1, sa);
      s[n] = sa;
    }
    __builtin_amdgcn_s_setprio(0);

#pragma unroll
    for (int n = 0; n < 4; n++)
#pragma unroll
      for (int r = 0; r < 4; r++)
        s[n][r] = exp2f(s[n][r]);
#pragma unroll
    for (int r = 0; r < 4; r++)
      l_acc[r] += (s[0][r] + s[1][r]) + (s[2][r] + s[3][r]);

#pragma unroll
    for (int n = 0; n < 4; n++)
#pragma unroll
      for (int r = 0; r < 4; r++) {
        int prow = lg * 4 + r;
        int key = n * 16 + lr;
        int idx = prow * 64 + (((key >> 3) ^ (prow & 7)) * 8) + (key & 7);
        pl[idx] = (__bf16)s[n][r];
      }
    asm volatile("s_waitcnt lgkmcnt(0)" ::: "memory");
    __builtin_amdgcn_sched_barrier(0);
    s16x8 pf0 = *(const s16x8*)(pl + lr * 64 + ((lg ^ (lr & 7)) * 8));
    s16x8 pf1 = *(const s16x8*)(pl + lr * 64 + (((4 + lg) ^ (lr & 7)) * 8));

    __builtin_amdgcn_s_setprio(1);
#pragma unroll
    for (int dt = 0; dt < 4; dt++) {
      int vrow = dt * 16 + lr, rx = vrow & 7;
      s16x8 vf0 = *(const s16x8*)(V_ + vrow * 64 + ((lg ^ rx) * 8));
      s16x8 vf1 = *(const s16x8*)(V_ + vrow * 64 + (((4 + lg) ^ rx) * 8));
      oacc[dt] = mfma_b(pf0, vf0, oacc[dt]);
      oacc[dt] = mfma_b(pf1, vf1, oacc[dt]);
    }
    __builtin_amdgcn_s_setprio(0);
    asm volatile("s_waitcnt lgkmcnt(0)" ::: "memory");
    __builtin_amdgcn_sched_barrier(0);
    BAR();
    cur ^= 1;
  }
  asm volatile("s_waitcnt vmcnt(0)" ::: "memory");

  float rinv[4];
#pragma unroll
  for (int r = 0; r < 4; r++) {
    float v = l_acc[r];
#pragma unroll
    for (int off = 1; off < 16; off <<= 1) v += __shfl_xor(v, off, 64);
    rinv[r] = 1.f / v;
  }

  int orow = qt * 128 + wave * 16 + (lg << 2);
#pragma unroll
  for (int dt = 0; dt < 4; dt++)
#pragma unroll
    for (int r = 0; r < 4; r++) {
      float v = oacc[dt][r] * rinv[r];
      O[(tok0 + orow + r) * 1024 + h * 64 + dt * 16 + lr] = (__bf16)v;
    }
}

// =====================================================================
// fused: self-gram(+Y) -> X' -> cross-gram -> Z -> LN+modulate -> znorm
// 4 rows per block. Writes Z (f32) and znorm (bf16); X' never stored.
// =====================================================================
__global__ __launch_bounds__(256)
void gram_fused(const float* __restrict__ X, const float* __restrict__ Y,
                const float* __restrict__ cls,
                const float* __restrict__ A_s, const float* __restrict__ B_s,
                const float* __restrict__ rms_s,
                const float* __restrict__ C_r, const float* __restrict__ D_r,
                const float* __restrict__ rms_c,
                const float* __restrict__ cproj,
                float* __restrict__ Z, __bf16* __restrict__ Znorm)
{
  __shared__ float xs[4][D_];
  __shared__ float tp[8][4][32];
  __shared__ float t1[4][32];
  __shared__ float red[4][4];
  __shared__ float red2[4][4][2];
  int row0 = blockIdx.x * 4;
  int b = row0 >> 10;
  int tid = threadIdx.x;
  int wv = tid >> 6;

  f32x4 cv = *(const f32x4*)(cls + (size_t)b * D_ + tid * 4);
  f32x4 yv[4];
#pragma unroll
  for (int rr = 0; rr < 4; rr++) {
    ((f32x4*)xs[rr])[tid] = *(const f32x4*)(X + (size_t)(row0 + rr) * D_ + tid * 4);
    yv[rr] = *(const f32x4*)(Y + (size_t)(row0 + rr) * D_ + tid * 4);
  }
  __syncthreads();

  // ---- stage 1: t1 = x @ A_s ----
  {
    int r = tid & 31, seg = tid >> 5;
    float a0 = 0.f, a1 = 0.f, a2 = 0.f, a3 = 0.f;
    const float* ap = A_s + r;
    for (int d = seg * 128; d < seg * 128 + 128; d++) {
      float w = ap[d * 32];
      a0 += xs[0][d] * w; a1 += xs[1][d] * w;
      a2 += xs[2][d] * w; a3 += xs[3][d] * w;
    }
    tp[seg][0][r] = a0; tp[seg][1][r] = a1; tp[seg][2][r] = a2; tp[seg][3][r] = a3;
  }
  __syncthreads();
  if (tid < 128) {
    int rr = tid >> 5, r = tid & 31;
    float sv = 0.f;
#pragma unroll
    for (int g = 0; g < 8; g++) sv += tp[g][rr][r];
    t1[rr][r] = sv;
  }
  __syncthreads();

  // ---- g = t1 @ B_s ; rms ; X' = scale*g*rs + Y ; pv = X' * cls ----
  f32x4 g[4] = {};
  for (int r = 0; r < 32; r++) {
    f32x4 bv = *(const f32x4*)(B_s + (size_t)r * D_ + tid * 4);
    g[0] += t1[0][r] * bv; g[1] += t1[1][r] * bv;
    g[2] += t1[2][r] * bv; g[3] += t1[3][r] * bv;
  }
  float ssl[4];
#pragma unroll
  for (int rr = 0; rr < 4; rr++)
    ssl[rr] = g[rr][0]*g[rr][0] + g[rr][1]*g[rr][1] + g[rr][2]*g[rr][2] + g[rr][3]*g[rr][3];
#pragma unroll
  for (int off = 1; off < 64; off <<= 1)
#pragma unroll
    for (int rr = 0; rr < 4; rr++) ssl[rr] += __shfl_xor(ssl[rr], off, 64);
  if ((tid & 63) == 0) {
#pragma unroll
    for (int rr = 0; rr < 4; rr++) red[wv][rr] = ssl[rr];
  }
  __syncthreads();
  {
    f32x4 scv = *(const f32x4*)(rms_s + tid * 4);
#pragma unroll
    for (int rr = 0; rr < 4; rr++) {
      float ss = red[0][rr] + red[1][rr] + red[2][rr] + red[3][rr];
      float rs = rsqrtf(ss * (1.f / D_) + 1e-6f);
      f32x4 xp = scv * g[rr] * rs + yv[rr];
      ((f32x4*)xs[rr])[tid] = xp * cv;
    }
  }
  __syncthreads();

  // ---- stage 2: t2 = (X'.cls) @ C_r ----
  {
    int r = tid & 31, seg = tid >> 5;
    float a0 = 0.f, a1 = 0.f, a2 = 0.f, a3 = 0.f;
    const float* cp = C_r + r;
    for (int d = seg * 128; d < seg * 128 + 128; d++) {
      float w = cp[d * 32];
      a0 += xs[0][d] * w; a1 += xs[1][d] * w;
      a2 += xs[2][d] * w; a3 += xs[3][d] * w;
    }
    tp[seg][0][r] = a0; tp[seg][1][r] = a1; tp[seg][2][r] = a2; tp[seg][3][r] = a3;
  }
  __syncthreads();
  if (tid < 128) {
    int rr = tid >> 5, r = tid & 31;
    float sv = 0.f;
#pragma unroll
    for (int g2i = 0; g2i < 8; g2i++) sv += tp[g2i][rr][r];
    t1[rr][r] = sv;
  }
  __syncthreads();

  // ---- g2 = t2 @ D_r ; rms -> z ----
  f32x4 g2[4] = {};
  for (int r = 0; r < 32; r++) {
    f32x4 bv = *(const f32x4*)(D_r + (size_t)r * D_ + tid * 4);
    g2[0] += t1[0][r] * bv; g2[1] += t1[1][r] * bv;
    g2[2] += t1[2][r] * bv; g2[3] += t1[3][r] * bv;
  }
#pragma unroll
  for (int rr = 0; rr < 4; rr++)
    ssl[rr] = g2[rr][0]*g2[rr][0] + g2[rr][1]*g2[rr][1] + g2[rr][2]*g2[rr][2] + g2[rr][3]*g2[rr][3];
#pragma unroll
  for (int off = 1; off < 64; off <<= 1)
#pragma unroll
    for (int rr = 0; rr < 4; rr++) ssl[rr] += __shfl_xor(ssl[rr], off, 64);
  if ((tid & 63) == 0) {
#pragma unroll
    for (int rr = 0; rr < 4; rr++) red[wv][rr] = ssl[rr];
  }
  __syncthreads();
  f32x4 z[4];
  {
    f32x4 scv = *(const f32x4*)(rms_c + tid * 4);
#pragma unroll
    for (int rr = 0; rr < 4; rr++) {
      float ss = red[0][rr] + red[1][rr] + red[2][rr] + red[3][rr];
      float rs = rsqrtf(ss * (1.f / D_) + 1e-6f);
      z[rr] = scv * g2[rr] * rs;
    }
  }

  // ---- LN + modulate of z -> znorm ----
  float s1l[4], s2l[4];
#pragma unroll
  for (int rr = 0; rr < 4; rr++) {
    s1l[rr] = z[rr][0] + z[rr][1] + z[rr][2] + z[rr][3];
    s2l[rr] = z[rr][0]*z[rr][0] + z[rr][1]*z[rr][1] + z[rr][2]*z[rr][2] + z[rr][3]*z[rr][3];
  }
#pragma unroll
  for (int off = 1; off < 64; off <<= 1)
#pragma unroll
    for (int rr = 0; rr < 4; rr++) {
      s1l[rr] += __shfl_xor(s1l[rr], off, 64);
      s2l[rr] += __shfl_xor(s2l[rr], off, 64);
    }
  if ((tid & 63) == 0) {
#pragma unroll
    for (int rr = 0; rr < 4; rr++) { red2[wv][rr][0] = s1l[rr]; red2[wv][rr][1] = s2l[rr]; }
  }
  __syncthreads();
  f32x4 shv = *(const f32x4*)(cproj + b * SIXD + 3072 + tid * 4);
  f32x4 scm = *(const f32x4*)(cproj + b * SIXD + 4096 + tid * 4);
#pragma unroll
  for (int rr = 0; rr < 4; rr++) {
    float S  = red2[0][rr][0] + red2[1][rr][0] + red2[2][rr][0] + red2[3][rr][0];
    float S2 = red2[0][rr][1] + red2[1][rr][1] + red2[2][rr][1] + red2[3][rr][1];
    float mean = S * (1.f / D_);
    float var  = S2 * (1.f / D_) - mean * mean;
    float rstd = rsqrtf(var + 1e-6f);
    f32x4 zn = (z[rr] - mean) * rstd * (scm + 1.f) + shv;
    *(f32x4*)(Z + (size_t)(row0 + rr) * D_ + tid * 4) = z[rr];
    bf16x4 o;
#pragma unroll
    for (int i = 0; i < 4; i++) o[i] = (__bf16)zn[i];
    *(bf16x4*)(Znorm + (size_t)(row0 + rr) * D_ + tid * 4) = o;
  }
}

// =====================================================================
extern "C" void kernel_launch(void* const* d_in, const int* in_sizes, int n_in,
                              void* d_out, int out_size, void* d_ws, size_t ws_size,
                              hipStream_t stream)
{
  const float* x     = (const float*)d_in[0];
  const float* c     = (const float*)d_in[1];
  const float* cls   = (const float*)d_in[2];
  const float* Wc    = (const float*)d_in[3];
  const float* bc    = (const float*)d_in[4];
  const float* Wqkv  = (const float*)d_in[5];
  const float* bqkv  = (const float*)d_in[6];
  const float* Wo    = (const float*)d_in[7];
  const float* bo    = (const float*)d_in[8];
  const float* A_s   = (const float*)d_in[9];
  const float* B_s   = (const float*)d_in[10];
  const float* rms_s = (const float*)d_in[11];
  const float* C_r   = (const float*)d_in[12];
  const float* D_r   = (const float*)d_in[13];
  const float* rms_c = (const float*)d_in[14];
  const float* W1    = (const float*)d_in[15];
  const float* b1    = (const float*)d_in[16];
  const float* W2    = (const float*)d_in[17];
  const float* b2    = (const float*)d_in[18];
  float* out = (float*)d_out;

  float* ws = (float*)d_ws;
  __bf16* Wqkvt = (__bf16*)(ws + 0);         // 3072x1024 bf16  [floats 0..1572864)
  __bf16* Wot   = (__bf16*)(ws + 1572864);   // 1024x1024       [..2097152)
  __bf16* W1t   = (__bf16*)(ws + 2097152);   // 4096x1024       [..4194304)
  __bf16* W2t   = (__bf16*)(ws + 4194304);   // 1024x4096       [..6291456)
  float*  cproj = ws + 6291456;              // 4x6144          [..6316032)
  __bf16* xnorm = (__bf16*)(ws + 6316032);   // 4096x1024 (also znorm)  [..8413184)
  __bf16* qkv   = (__bf16*)(ws + 8413184);   // 4096x3072       [..14704640)
  __bf16* Vt    = (__bf16*)(ws + 14704640);  // 64x64x1024      [..16801792)
  __bf16* h1    = (__bf16*)(ws + 8413184);   // 4096x4096 (reuses qkv+Vt)
  __bf16* attno = (__bf16*)(ws + 16801792);  // 4096x1024       [..18898944)
  float*  Ybuf  = ws + 18898944;             // 4096x1024 f32 (Y)  [..20996096)
  // W2 split-K(4) bf16 partials, 8 MB each, in regions dead at W2-GEMM time.
  // W2t [4194304..6291456) and h1 [8413184..16801792) are NOT touched.
  __bf16* P0 = (__bf16*)(ws + 0);            // over Wqkvt+Wot (dead)
  __bf16* P1 = (__bf16*)(ws + 2097152);      // over W1t (dead after W1 GEMM)
  __bf16* P2 = (__bf16*)(ws + 16801792);     // over attno (dead after Wo GEMM)
  __bf16* P3 = (__bf16*)(ws + 18898944);     // over Ybuf (dead after gram_fused)

  prep<<<3264, 256, 0, stream>>>(c, Wc, bc, cproj,
                                 Wqkv, Wo, W1, W2, Wqkvt, Wot, W1t, W2t);
  ln_mod<<<4096, 256, 0, stream>>>(x, cproj, 0, 1024, xnorm);
  gemm256<4, 16, 1024><<<192, 512, 0, stream>>>(xnorm, Wqkvt, bqkv,
                                                qkv, nullptr, nullptr, nullptr,
                                                4096, 3072);
  transpose_v<<<4096, 256, 0, stream>>>(qkv, Vt);
  attn_flash<<<512, 512, 0, stream>>>(qkv, Vt, attno);
  gemm_bt<1, 4><<<256, 256, 0, stream>>>(attno, Wot, bo, cproj, 2048, x,
                                         Ybuf, nullptr, nullptr, nullptr,
                                         4096, 1024, 1024, 1);
  gram_fused<<<1024, 256, 0, stream>>>(x, Ybuf, cls, A_s, B_s, rms_s,
                                       C_r, D_r, rms_c, cproj, out, xnorm);
  gemm256<2, 16, 1024><<<256, 512, 0, stream>>>(xnorm, W1t, b1,
                                                h1, nullptr, nullptr, nullptr,
                                                4096, 4096);
  gemm256<3, 16, 4096><<<256, 512, 0, stream>>>(h1, W2t, nullptr,
                                                P0, P1, P2, P3, 4096, 1024);
  reduce_w2<<<4096, 256, 0, stream>>>(P0, P1, P2, P3, b2, cproj, out);
}

// Round 7
// 253.437 us; speedup vs baseline: 1.3313x; 1.0121x over previous
//
#include <hip/hip_runtime.h>
#include <stdint.h>

typedef float  f32x4  __attribute__((ext_vector_type(4)));
typedef short  s16x8  __attribute__((ext_vector_type(8)));   // 8 bf16 (4 VGPRs)
typedef __bf16 bf16x4 __attribute__((ext_vector_type(4)));
typedef __bf16 bf16x8 __attribute__((ext_vector_type(8)));

#define D_    1024
#define SIXD  6144
// 0.125 (1/sqrt(64)) * log2(e): folded into Q so attn P = exp2(S) directly
#define QSCALE 0.18033688011112042f

#define BAR() asm volatile("s_barrier" ::: "memory")

// builtin MFMA: compiler owns acc registers + per-use counted lgkmcnt waits
__device__ __forceinline__ f32x4 mfma_b(const s16x8 &a, const s16x8 &b, const f32x4 &c) {
  return __builtin_amdgcn_mfma_f32_16x16x32_bf16(a, b, c, 0, 0, 0);
}

__device__ __forceinline__ void gload_lds16(const void* g, void* l) {
  __builtin_amdgcn_global_load_lds(
      (const __attribute__((address_space(1))) uint32_t*)g,
      (__attribute__((address_space(3))) uint32_t*)l, 16, 0, 0);
}

// =====================================================================
// prep: fused cond_gemm (blocks 0..191) + weight transposes (192..959)
//  cond: cproj[b,:] = silu(c[b,:]) @ Wc + bc
//  transpose: fp32 W -> bf16 W^T; each block does a 256(K)x64(N) strip
//  (4 stacked 64x64 tiles), 256B read / 128B write per thread, 16B stores.
// =====================================================================
__global__ __launch_bounds__(256)
void prep(const float* __restrict__ c, const float* __restrict__ Wc,
          const float* __restrict__ bc, float* __restrict__ cproj,
          const float* __restrict__ Wqkv, const float* __restrict__ Wo,
          const float* __restrict__ W1, const float* __restrict__ W2,
          __bf16* __restrict__ Wqkvt, __bf16* __restrict__ Wot,
          __bf16* __restrict__ W1t, __bf16* __restrict__ W2t)
{
  __shared__ __align__(16) char smem[33280];   // union: cond 20.5KB | transpose 33.3KB
  int tid = threadIdx.x;
  if (blockIdx.x < 192) {
    float* sc = (float*)smem;                         // [4096]
    float (*tp)[4][32] = (float(*)[4][32])(smem + 16384);  // [8][4][32]
    for (int i = tid; i < 4096; i += 256) {
      float v = c[i];
      sc[i] = v / (1.f + __expf(-v));
    }
    __syncthreads();
    int colo = tid & 31, kseg = tid >> 5;
    int col = blockIdx.x * 32 + colo;
    float a0 = 0.f, a1 = 0.f, a2 = 0.f, a3 = 0.f;
    for (int k = kseg * 128; k < kseg * 128 + 128; k++) {
      float w = Wc[(size_t)k * SIXD + col];
      a0 += sc[k] * w; a1 += sc[1024 + k] * w;
      a2 += sc[2048 + k] * w; a3 += sc[3072 + k] * w;
    }
    tp[kseg][0][colo] = a0; tp[kseg][1][colo] = a1;
    tp[kseg][2][colo] = a2; tp[kseg][3][colo] = a3;
    __syncthreads();
    if (kseg == 0) {
#pragma unroll
      for (int b = 0; b < 4; b++) {
        float s = bc[col];
#pragma unroll
        for (int g = 0; g < 8; g++) s += tp[g][b][colo];
        cproj[b * SIXD + col] = s;
      }
    }
    return;
  }
  int bid = blockIdx.x - 192;
  const float* W; __bf16* Wt; int Kdim, Ndim, lb;
  if (bid < 192)      { W = Wqkv; Wt = Wqkvt; Kdim = 1024; Ndim = 3072; lb = bid; }
  else if (bid < 256) { W = Wo;   Wt = Wot;   Kdim = 1024; Ndim = 1024; lb = bid - 192; }
  else if (bid < 512) { W = W1;   Wt = W1t;   Kdim = 1024; Ndim = 4096; lb = bid - 256; }
  else                { W = W2;   Wt = W2t;   Kdim = 4096; Ndim = 1024; lb = bid - 512; }
  int ntn = Ndim >> 6;
  int ktg = lb / ntn, nt = lb % ntn;
  __bf16* tt = (__bf16*)smem;                 // [4*64][65]
  const float* src = W + (size_t)(ktg * 256) * Ndim + nt * 64;
  int krow = tid >> 4, c4 = tid & 15;
#pragma unroll
  for (int t = 0; t < 4; t++) {
#pragma unroll
    for (int i = 0; i < 4; i++) {
      int k = i * 16 + krow;
      float4 v = ((const float4*)(src + (size_t)(t * 64 + k) * Ndim))[c4];
      __bf16* row = tt + (t * 64 + k) * 65 + c4 * 4;
      row[0] = (__bf16)v.x; row[1] = (__bf16)v.y;
      row[2] = (__bf16)v.z; row[3] = (__bf16)v.w;
    }
  }
  __syncthreads();
  __bf16* dst = Wt + (size_t)(nt * 64) * Kdim + ktg * 256;
  int n = tid >> 2, ks = (tid & 3) * 16;
#pragma unroll
  for (int t = 0; t < 4; t++) {
    bf16x8 lo, hi;
#pragma unroll
    for (int j = 0; j < 8; j++) {
      lo[j] = tt[(t * 64 + ks + j) * 65 + n];
      hi[j] = tt[(t * 64 + ks + 8 + j) * 65 + n];
    }
    __bf16* dp = dst + (size_t)n * Kdim + t * 64 + ks;
    *(bf16x8*)(dp) = lo;
    *(bf16x8*)(dp + 8) = hi;
  }
}

// =====================================================================
// fused LayerNorm + modulate, fp32 in -> bf16 out
// =====================================================================
__global__ __launch_bounds__(256)
void ln_mod(const float* __restrict__ X, const float* __restrict__ cproj,
            int shift_off, int scale_off, __bf16* __restrict__ Out)
{
  int row = blockIdx.x;
  int b = row >> 10;
  int tid = threadIdx.x;
  const float4* xr = (const float4*)(X + (size_t)row * D_);
  float4 v = xr[tid];
  float s  = v.x + v.y + v.z + v.w;
  float s2 = v.x * v.x + v.y * v.y + v.z * v.z + v.w * v.w;
#pragma unroll
  for (int off = 1; off < 64; off <<= 1) {
    s  += __shfl_xor(s,  off, 64);
    s2 += __shfl_xor(s2, off, 64);
  }
  __shared__ float red[8];
  int wave = tid >> 6, lane = tid & 63;
  if (lane == 0) { red[wave] = s; red[4 + wave] = s2; }
  __syncthreads();
  s  = red[0] + red[1] + red[2] + red[3];
  s2 = red[4] + red[5] + red[6] + red[7];
  float mean = s * (1.f / D_);
  float var  = s2 * (1.f / D_) - mean * mean;
  float rstd = rsqrtf(var + 1e-6f);
  const float4* sh = (const float4*)(cproj + b * SIXD + shift_off);
  const float4* sc = (const float4*)(cproj + b * SIXD + scale_off);
  float4 shv = sh[tid], scv = sc[tid];
  bf16x4 o;
  o[0] = (__bf16)((v.x - mean) * rstd * (1.f + scv.x) + shv.x);
  o[1] = (__bf16)((v.y - mean) * rstd * (1.f + scv.y) + shv.y);
  o[2] = (__bf16)((v.z - mean) * rstd * (1.f + scv.z) + shv.z);
  o[3] = (__bf16)((v.w - mean) * rstd * (1.f + scv.w) + shv.w);
  *(bf16x4*)(Out + (size_t)row * D_ + tid * 4) = o;
}

// =====================================================================
// bf16 MFMA GEMM, C = A(MxK) @ Bt(NxK)^T, 128x128 tile, BK=32.
// NBUF-deep LDS pipeline, XCD-swizzled grid. (Used for Wo: N=1024)
// EPI 1: f32 = resid + gate * (acc + bias)
// =====================================================================
template<int EPI, int NBUF>
__global__ __launch_bounds__(256)
void gemm_bt(const __bf16* __restrict__ A, const __bf16* __restrict__ Bt,
             const float* __restrict__ bias, const float* __restrict__ cproj,
             int gate_off, const float* __restrict__ resid,
             void* __restrict__ Cout, void* __restrict__ Cout2,
             void* __restrict__ Cout3, void* __restrict__ Cout4,
             int M, int N, int K, int SK)
{
  __shared__ __align__(16) __bf16 As[NBUF * 128 * 32];
  __shared__ __align__(16) __bf16 Bs[NBUF * 128 * 32];
  const int PD = NBUF - 1;
  int tilesN = N >> 7, tilesM = M >> 7;
  int npersk = tilesM * tilesN;
  int sk = blockIdx.x / npersk;
  int rest = blockIdx.x % npersk;
  int cpx = npersk >> 3;
  rest = (rest & 7) * cpx + (rest >> 3);   // XCD-contiguous chunks
  int bm = rest / tilesN, bn = rest % tilesN;
  int Klen = K / SK, Kstart = sk * Klen;

  int tid = threadIdx.x;
  int lane = tid & 63, wave = tid >> 6;
  int lr = lane & 15, lg = lane >> 4;
  int wm = (wave >> 1) << 6, wn = (wave & 1) << 6;

  f32x4 acc[4][4] = {};

  int sr = tid >> 2, skb = tid & 3;
  int scol = ((skb ^ ((sr >> 1) & 3)) * 8);
  const __bf16* pa = A + (size_t)((bm << 7) + sr) * K + Kstart + scol;
  const __bf16* pb = Bt + (size_t)((bn << 7) + sr) * K + Kstart + scol;
  const size_t rstep = (size_t)64 * K;
  __bf16* la = As + tid * 8;
  __bf16* lb = Bs + tid * 8;

  auto STAGE = [&](int buf, int k0) {
    int bo = buf * 4096;
    gload_lds16(pa + k0, la + bo);
    gload_lds16(pa + rstep + k0, la + bo + 2048);
    gload_lds16(pb + k0, lb + bo);
    gload_lds16(pb + rstep + k0, lb + bo + 2048);
  };

  int nt = Klen >> 5;
#pragma unroll
  for (int p = 0; p < PD; p++) STAGE(p, p * 32);

  for (int t = 0; t < nt; t++) {
    if (t + PD < nt) STAGE((t + PD) % NBUF, (t + PD) * 32);
    int ahead = nt - 1 - t; if (ahead > PD) ahead = PD;
    if (ahead >= 3)      asm volatile("s_waitcnt vmcnt(12)" ::: "memory");
    else if (ahead == 2) asm volatile("s_waitcnt vmcnt(8)" ::: "memory");
    else if (ahead == 1) asm volatile("s_waitcnt vmcnt(4)" ::: "memory");
    else                 asm volatile("s_waitcnt vmcnt(0)" ::: "memory");
    BAR();
    const __bf16* Ac = As + (t % NBUF) * 4096;
    const __bf16* Bc = Bs + (t % NBUF) * 4096;
    s16x8 af[4], bfv[4];
#pragma unroll
    for (int m = 0; m < 4; m++) {
      int row = wm + m * 16 + lr;
      af[m] = *(const s16x8*)(Ac + row * 32 + ((lg ^ ((row >> 1) & 3)) * 8));
    }
#pragma unroll
    for (int n = 0; n < 4; n++) {
      int row = wn + n * 16 + lr;
      bfv[n] = *(const s16x8*)(Bc + row * 32 + ((lg ^ ((row >> 1) & 3)) * 8));
    }
    asm volatile("s_waitcnt lgkmcnt(0)" ::: "memory");
    __builtin_amdgcn_sched_barrier(0);
    BAR();
    __builtin_amdgcn_s_setprio(1);
#pragma unroll
    for (int m = 0; m < 4; m++)
#pragma unroll
      for (int n = 0; n < 4; n++)
        acc[m][n] = mfma_b(af[m], bfv[n], acc[m][n]);
    __builtin_amdgcn_s_setprio(0);
  }
  asm volatile("s_waitcnt vmcnt(0)" ::: "memory");

  __bf16* Pp = nullptr;
  if (EPI == 3) {
    if (sk == 0)      Pp = (__bf16*)Cout;
    else if (sk == 1) Pp = (__bf16*)Cout2;
    else if (sk == 2) Pp = (__bf16*)Cout3;
    else              Pp = (__bf16*)Cout4;
  }

  int row0 = (bm << 7) + wm;
  int col0 = (bn << 7) + wn;
#pragma unroll
  for (int m = 0; m < 4; m++) {
#pragma unroll
    for (int n = 0; n < 4; n++) {
      int cc = col0 + n * 16 + lr;
      float bv = (EPI == 3) ? 0.f : bias[cc];
#pragma unroll
      for (int r = 0; r < 4; r++) {
        int row = row0 + m * 16 + (lg << 2) + r;
        float v = acc[m][n][r] + bv;
        size_t idx = (size_t)row * N + cc;
        if (EPI == 0) {
          ((__bf16*)Cout)[idx] = (__bf16)v;
        } else if (EPI == 1) {
          int b = row >> 10;
          float g = cproj[b * SIXD + gate_off + cc];
          ((float*)Cout)[idx] = resid[idx] + g * v;
        } else if (EPI == 2) {
          float u = 0.7978845608028654f * (v + 0.044715f * v * v * v);
          u = fminf(fmaxf(u, -15.f), 15.f);
          float e = __expf(2.f * u);
          float th = (e - 1.f) / (e + 1.f);
          ((__bf16*)Cout)[idx] = (__bf16)(0.5f * v * (1.f + th));
        } else if (EPI == 4) {
          float scq = (cc < 1024) ? QSCALE : 1.f;
          ((__bf16*)Cout)[idx] = (__bf16)(v * scq);
        } else {
          Pp[idx] = (__bf16)v;
        }
      }
    }
  }
}

// =====================================================================
// 256x256-tile deep-pipelined 3-phase bf16 MFMA GEMM (r3 schedule,
// builtin MFMA). BK=64, 8 waves (2M x 4N), 512 threads, 128 KiB LDS.
// Per wave: 128x64 output, acc[8][4] f32x4 (compiler-allocated).
//  P1: read b1(t);  MFMA Q1(alo x b0);             lgkm0; BAR  (b1 drained)
//  P2: read ahi(t); SB(t+2,q0,q1); MFMA Q2(alo x b1); lgkm0; BAR (ahi drained)
//  P3: SB(t+2,q2,q3)+SA(t+2,q0-q3); MFMA Q3+Q4 (32);
//      vmcnt(8) [only t+2's 8 left -> t+1 landed]; BAR;
//      pre-read alo(t+1), b0(t+1)
// EPI 2: bf16 = gelu_tanh(acc + bias)
// EPI 3: bf16 partial = acc -> Pk[sk]
// EPI 5: qkv fused: col<1024 -> qkv*QSCALE | <2048 -> qkv | else -> Vt
//        transposed (Vt[b*1024+dd][ntok] = acc, one bf16x4 store per lane)
// =====================================================================
template<int EPI, int NT, int KD>
__global__ __launch_bounds__(512, 2)
void gemm256(const __bf16* __restrict__ A, const __bf16* __restrict__ Bt,
             const float* __restrict__ bias,
             void* __restrict__ Cout, void* __restrict__ Cout2,
             void* __restrict__ Cout3, void* __restrict__ Cout4,
             int M, int N)
{
  __shared__ __align__(16) __bf16 As[2 * 16384];   // 2 x 256x64
  __shared__ __align__(16) __bf16 Bs[2 * 16384];
  int tilesN = N >> 8, tilesM = M >> 8;
  int npersk = tilesM * tilesN;
  int sk = blockIdx.x / npersk;
  int rest = blockIdx.x % npersk;
  int cpx = npersk >> 3;
  rest = (rest & 7) * cpx + (rest >> 3);   // XCD-contiguous chunks
  int bm = rest / tilesN, bn = rest % tilesN;
  int Kstart = sk * (NT * 64);

  int tid = threadIdx.x;
  int lane = tid & 63, wave = tid >> 6;
  int lr = lane & 15, lg = lane >> 4;
  int wr = wave >> 2, wc = wave & 3;

  f32x4 acc[8][4] = {};

  // staging: one gload covers 64 rows x 64 k; thread -> (row=tid>>3, chunk)
  int srow = tid >> 3;
  int schunk = (tid & 7) ^ (srow & 7);     // pre-swizzled global source
  const __bf16* pa = A  + (size_t)((bm << 8) + srow) * KD + Kstart + schunk * 8;
  const __bf16* pb = Bt + (size_t)((bn << 8) + srow) * KD + Kstart + schunk * 8;
  __bf16* la = As + tid * 8;
  __bf16* lb = Bs + tid * 8;

  // quarter q (64 rows) of tile t
  auto SAq = [&](int t, int q) {
    gload_lds16(pa + (size_t)(q * 64) * KD + t * 64,
                la + (t & 1) * 16384 + q * 4096);
  };
  auto SBq = [&](int t, int q) {
    gload_lds16(pb + (size_t)(q * 64) * KD + t * 64,
                lb + (t & 1) * 16384 + q * 4096);
  };

  // prologue: A(0),B(0) then A(1),B(1)
#pragma unroll
  for (int q = 0; q < 4; q++) { SAq(0, q); }
#pragma unroll
  for (int q = 0; q < 4; q++) { SBq(0, q); }
#pragma unroll
  for (int q = 0; q < 4; q++) { SAq(1, q); }
#pragma unroll
  for (int q = 0; q < 4; q++) { SBq(1, q); }
  asm volatile("s_waitcnt vmcnt(8)" ::: "memory");  // A(0),B(0) landed
  BAR();

  // ds_read addressing: row*128B + ((kchunk ^ (row&7))*16); row&7 == lr&7
  int cc0 = ((lg ^ (lr & 7)) << 4);
  int cc1 = cc0 ^ 64;
  const char* aA = (const char*)As + (wr * 128 + lr) * 128;
  const char* aB = (const char*)Bs + (wc * 64 + lr) * 128;

  s16x8 alo[4][2], ahi[4][2], b0v[2][2], b1v[2][2];
  // pre-read frags needed by Q1(0)
#pragma unroll
  for (int m = 0; m < 4; m++) {
    alo[m][0] = *(const s16x8*)(aA + m * 2048 + cc0);
    alo[m][1] = *(const s16x8*)(aA + m * 2048 + cc1);
  }
#pragma unroll
  for (int n = 0; n < 2; n++) {
    b0v[n][0] = *(const s16x8*)(aB + n * 2048 + cc0);
    b0v[n][1] = *(const s16x8*)(aB + n * 2048 + cc1);
  }

  for (int t = 0; t < NT; t++) {
    const char* Ab = aA + (t & 1) * 32768;
    const char* Bb = aB + (t & 1) * 32768;

    // ---------- P1: read b1(t); Q1 = alo x b0
#pragma unroll
    for (int n = 0; n < 2; n++) {
      b1v[n][0] = *(const s16x8*)(Bb + 4096 + n * 2048 + cc0);
      b1v[n][1] = *(const s16x8*)(Bb + 4096 + n * 2048 + cc1);
    }
    __builtin_amdgcn_sched_barrier(0);
    __builtin_amdgcn_s_setprio(1);
#pragma unroll
    for (int m = 0; m < 4; m++)
#pragma unroll
      for (int n = 0; n < 2; n++) {
        acc[m][n] = mfma_b(alo[m][0], b0v[n][0], acc[m][n]);
        acc[m][n] = mfma_b(alo[m][1], b0v[n][1], acc[m][n]);
      }
    __builtin_amdgcn_s_setprio(0);
    asm volatile("s_waitcnt lgkmcnt(0)" ::: "memory");  // b1(t) drained
    BAR();

    // ---------- P2: read ahi(t); stage B(t+2) q0,q1; Q2 = alo x b1
#pragma unroll
    for (int m = 0; m < 4; m++) {
      ahi[m][0] = *(const s16x8*)(Ab + 8192 + m * 2048 + cc0);
      ahi[m][1] = *(const s16x8*)(Ab + 8192 + m * 2048 + cc1);
    }
    if (t + 2 < NT) { SBq(t + 2, 0); SBq(t + 2, 1); }
    __builtin_amdgcn_sched_barrier(0);
    __builtin_amdgcn_s_setprio(1);
#pragma unroll
    for (int m = 0; m < 4; m++)
#pragma unroll
      for (int n = 0; n < 2; n++) {
        acc[m][2 + n] = mfma_b(alo[m][0], b1v[n][0], acc[m][2 + n]);
        acc[m][2 + n] = mfma_b(alo[m][1], b1v[n][1], acc[m][2 + n]);
      }
    __builtin_amdgcn_s_setprio(0);
    asm volatile("s_waitcnt lgkmcnt(0)" ::: "memory");  // ahi(t) drained
    BAR();

    // ---------- P3: stage B(t+2) q2,q3 + A(t+2) q0-q3; Q3+Q4; vmcnt; BAR
    if (t + 2 < NT) {
      SBq(t + 2, 2); SBq(t + 2, 3);
      SAq(t + 2, 0); SAq(t + 2, 1); SAq(t + 2, 2); SAq(t + 2, 3);
    }
    __builtin_amdgcn_sched_barrier(0);
    __builtin_amdgcn_s_setprio(1);
#pragma unroll
    for (int m = 0; m < 4; m++)
#pragma unroll
      for (int n = 0; n < 2; n++) {
        acc[4 + m][2 + n] = mfma_b(ahi[m][0], b1v[n][0], acc[4 + m][2 + n]);
        acc[4 + m][2 + n] = mfma_b(ahi[m][1], b1v[n][1], acc[4 + m][2 + n]);
      }
#pragma unroll
    for (int m = 0; m < 4; m++)
#pragma unroll
      for (int n = 0; n < 2; n++) {
        acc[4 + m][n] = mfma_b(ahi[m][0], b0v[n][0], acc[4 + m][n]);
        acc[4 + m][n] = mfma_b(ahi[m][1], b0v[n][1], acc[4 + m][n]);
      }
    __builtin_amdgcn_s_setprio(0);
    if (t + 1 < NT) {
      if (t + 2 < NT) asm volatile("s_waitcnt vmcnt(8)" ::: "memory");
      else            asm volatile("s_waitcnt vmcnt(0)" ::: "memory");
      BAR();   // all waves: A(t+1),B(t+1) fully landed
      const char* An = aA + ((t + 1) & 1) * 32768;
      const char* Bn = aB + ((t + 1) & 1) * 32768;
#pragma unroll
      for (int m = 0; m < 4; m++) {
        alo[m][0] = *(const s16x8*)(An + m * 2048 + cc0);
        alo[m][1] = *(const s16x8*)(An + m * 2048 + cc1);
      }
#pragma unroll
      for (int n = 0; n < 2; n++) {
        b0v[n][0] = *(const s16x8*)(Bn + n * 2048 + cc0);
        b0v[n][1] = *(const s16x8*)(Bn + n * 2048 + cc1);
      }
    }
  }
  asm volatile("s_waitcnt lgkmcnt(0)" ::: "memory");

  __bf16* Pp = nullptr;
  if (EPI == 3) {
    if (sk == 0)      Pp = (__bf16*)Cout;
    else if (sk == 1) Pp = (__bf16*)Cout2;
    else if (sk == 2) Pp = (__bf16*)Cout3;
    else              Pp = (__bf16*)Cout4;
  }

  int row0 = (bm << 8) + wr * 128;
  int col0 = (bn << 8) + wc * 64;
#pragma unroll
  for (int m = 0; m < 8; m++) {
#pragma unroll
    for (int n = 0; n < 4; n++) {
      int cc = col0 + n * 16 + lr;
      float bv = (EPI == 3) ? 0.f : bias[cc];
      if (EPI == 5 && cc >= 2048) {
        // V-part: write transposed into Vt (Cout2); 4 consecutive tokens
        int rbase = row0 + m * 16 + (lg << 2);
        int dd = cc - 2048;
        int bb = rbase >> 10, ntok = rbase & 1023;
        bf16x4 o;
#pragma unroll
        for (int r = 0; r < 4; r++) o[r] = (__bf16)(acc[m][n][r] + bv);
        *(bf16x4*)((__bf16*)Cout2 + ((size_t)(bb << 10) + dd) * 1024 + ntok) = o;
        continue;
      }
#pragma unroll
      for (int r = 0; r < 4; r++) {
        int row = row0 + m * 16 + (lg << 2) + r;
        float v = acc[m][n][r] + bv;
        size_t idx = (size_t)row * N + cc;
        if (EPI == 2) {
          float u = 0.7978845608028654f * (v + 0.044715f * v * v * v);
          u = fminf(fmaxf(u, -15.f), 15.f);
          float e = __expf(2.f * u);
          float th = (e - 1.f) / (e + 1.f);
          ((__bf16*)Cout)[idx] = (__bf16)(0.5f * v * (1.f + th));
        } else if (EPI == 5) {
          float scq = (cc < 1024) ? QSCALE : 1.f;
          ((__bf16*)Cout)[idx] = (__bf16)(v * scq);
        } else {
          Pp[idx] = (__bf16)v;
        }
      }
    }
  }
}

// =====================================================================
// W2 split-K(4) reduce, bf16 partials (4 scattered buffers):
//   Out = Out + gate[b,col] * (P0+P1+P2+P3 + bias[col])   (in place on Z)
// =====================================================================
__global__ __launch_bounds__(256)
void reduce_w2(const __bf16* __restrict__ P0, const __bf16* __restrict__ P1,
               const __bf16* __restrict__ P2, const __bf16* __restrict__ P3,
               const float* __restrict__ bias, const float* __restrict__ cproj,
               float* __restrict__ Out)
{
  int row = blockIdx.x;
  int b = row >> 10;
  int tid = threadIdx.x;
  size_t base = (size_t)row * D_ + tid * 4;
  bf16x4 a0 = *(const bf16x4*)(P0 + base);
  bf16x4 a1 = *(const bf16x4*)(P1 + base);
  bf16x4 a2 = *(const bf16x4*)(P2 + base);
  bf16x4 a3 = *(const bf16x4*)(P3 + base);
  f32x4 s;
#pragma unroll
  for (int i = 0; i < 4; i++)
    s[i] = ((float)a0[i] + (float)a1[i]) + ((float)a2[i] + (float)a3[i]);
  f32x4 bz = *(const f32x4*)(bias + tid * 4);
  f32x4 g  = *(const f32x4*)(cproj + b * SIXD + 5120 + tid * 4);
  f32x4 z  = *(const f32x4*)(Out + base);
  *(f32x4*)(Out + base) = z + g * (s + bz);
}

// =====================================================================
// flash attention, no-max softmax (Q pre-scaled so P = exp2(S)).
// 8 waves = 128 q rows of one (b,h); KVBLK=64, double-buffered staging.
// =====================================================================
__global__ __launch_bounds__(512, 4)
void attn_flash(const __bf16* __restrict__ qkv, const __bf16* __restrict__ Vt,
                __bf16* __restrict__ O)
{
  __shared__ __align__(16) __bf16 Kl[2][64 * 64];
  __shared__ __align__(16) __bf16 Vl[2][64 * 64];
  __shared__ __align__(16) __bf16 Pl[8][16 * 64];

  int bid = ((blockIdx.x & 7) << 6) | (blockIdx.x >> 3);  // XCD swizzle
  int qt = bid & 7, h = (bid >> 3) & 15, b = bid >> 7;
  int tid = threadIdx.x, wave = tid >> 6, lane = tid & 63;
  int lr = lane & 15, lg = lane >> 4;

  size_t tok0 = (size_t)b * 1024;
  int qrow = qt * 128 + wave * 16 + lr;
  const __bf16* qptr = qkv + (tok0 + qrow) * 3072 + h * 64;
  s16x8 qf0 = *(const s16x8*)(qptr + lg * 8);
  s16x8 qf1 = *(const s16x8*)(qptr + 32 + lg * 8);

  float l_acc[4] = {0.f, 0.f, 0.f, 0.f};
  f32x4 oacc[4] = {};

  const __bf16* kbase = qkv + tok0 * 3072 + 1024 + h * 64;
  const __bf16* vbase = Vt + ((size_t)(b * 16 + h) * 64) * 1024;

  int skey = tid >> 3, sdb = tid & 7;
  const __bf16* ksrc = kbase + (size_t)skey * 3072 + ((sdb ^ (skey & 7)) * 8);
  const __bf16* vsrc = vbase + (size_t)skey * 1024 + ((sdb ^ (skey & 7)) * 8);
  __bf16* klp = &Kl[0][0] + tid * 8;
  __bf16* vlp = &Vl[0][0] + tid * 8;
  __bf16* pl = &Pl[wave][0];

  auto STAGE = [&](int buf, int kk) {
    gload_lds16(ksrc + (size_t)kk * 3072, klp + buf * 4096);
    gload_lds16(vsrc + kk, vlp + buf * 4096);
  };

  STAGE(0, 0);
  int cur = 0;
  for (int k0 = 0; k0 < 1024; k0 += 64) {
    int kn = (k0 + 64 < 1024) ? (k0 + 64) : k0;
    STAGE(cur ^ 1, kn);
    asm volatile("s_waitcnt vmcnt(2)" ::: "memory");
    BAR();
    const __bf16* K_ = &Kl[cur][0];
    const __bf16* V_ = &Vl[cur][0];

    f32x4 s[4];
    __builtin_amdgcn_s_setprio(1);
#pragma unroll
    for (int n = 0; n < 4; n++) {
      int key = n * 16 + lr;
      int kx = key & 7;
      s16x8 kf0 = *(const s16x8*)(K_ + key * 64 + ((lg ^ kx) * 8));
      s16x8 kf1 = *(const s16x8*)(K_ + key * 64 + (((4 + lg) ^ kx) * 8));
      f32x4 sa = {0.f, 0.f, 0.f, 0.f};
      sa = mfma_b(qf0, kf0, sa);
      sa = mfma_b(qf1, kf1, sa);
      s[n] = sa;
    }
    __builtin_amdgcn_s_setprio(0);

#pragma unroll
    for (int n = 0; n < 4; n++)
#pragma unroll
      for (int r = 0; r < 4; r++)
        s[n][r] = exp2f(s[n][r]);
#pragma unroll
    for (int r = 0; r < 4; r++)
      l_acc[r] += (s[0][r] + s[1][r]) + (s[2][r] + s[3][r]);

#pragma unroll
    for (int n = 0; n < 4; n++)
#pragma unroll
      for (int r = 0; r < 4; r++) {
        int prow = lg * 4 + r;
        int key = n * 16 + lr;
        int idx = prow * 64 + (((key >> 3) ^ (prow & 7)) * 8) + (key & 7);
        pl[idx] = (__bf16)s[n][r];
      }
    asm volatile("s_waitcnt lgkmcnt(0)" ::: "memory");
    __builtin_amdgcn_sched_barrier(0);
    s16x8 pf0 = *(const s16x8*)(pl + lr * 64 + ((lg ^ (lr & 7)) * 8));
    s16x8 pf1 = *(const s16x8*)(pl + lr * 64 + (((4 + lg) ^ (lr & 7)) * 8));

    __builtin_amdgcn_s_setprio(1);
#pragma unroll
    for (int dt = 0; dt < 4; dt++) {
      int vrow = dt * 16 + lr, rx = vrow & 7;
      s16x8 vf0 = *(const s16x8*)(V_ + vrow * 64 + ((lg ^ rx) * 8));
      s16x8 vf1 = *(const s16x8*)(V_ + vrow * 64 + (((4 + lg) ^ rx) * 8));
      oacc[dt] = mfma_b(pf0, vf0, oacc[dt]);
      oacc[dt] = mfma_b(pf1, vf1, oacc[dt]);
    }
    __builtin_amdgcn_s_setprio(0);
    asm volatile("s_waitcnt lgkmcnt(0)" ::: "memory");
    __builtin_amdgcn_sched_barrier(0);
    BAR();
    cur ^= 1;
  }
  asm volatile("s_waitcnt vmcnt(0)" ::: "memory");

  float rinv[4];
#pragma unroll
  for (int r = 0; r < 4; r++) {
    float v = l_acc[r];
#pragma unroll
    for (int off = 1; off < 16; off <<= 1) v += __shfl_xor(v, off, 64);
    rinv[r] = 1.f / v;
  }

  int orow = qt * 128 + wave * 16 + (lg << 2);
#pragma unroll
  for (int dt = 0; dt < 4; dt++)
#pragma unroll
    for (int r = 0; r < 4; r++) {
      float v = oacc[dt][r] * rinv[r];
      O[(tok0 + orow + r) * 1024 + h * 64 + dt * 16 + lr] = (__bf16)v;
    }
}

// =====================================================================
// fused: self-gram(+Y) -> X' -> cross-gram -> Z -> LN+modulate -> znorm
// 4 rows per block. Writes Z (f32) and znorm (bf16); X' never stored.
// =====================================================================
__global__ __launch_bounds__(256)
void gram_fused(const float* __restrict__ X, const float* __restrict__ Y,
                const float* __restrict__ cls,
                const float* __restrict__ A_s, const float* __restrict__ B_s,
                const float* __restrict__ rms_s,
                const float* __restrict__ C_r, const float* __restrict__ D_r,
                const float* __restrict__ rms_c,
                const float* __restrict__ cproj,
                float* __restrict__ Z, __bf16* __restrict__ Znorm)
{
  __shared__ float xs[4][D_];
  __shared__ float tp[8][4][32];
  __shared__ float t1[4][32];
  __shared__ float red[4][4];
  __shared__ float red2[4][4][2];
  int row0 = blockIdx.x * 4;
  int b = row0 >> 10;
  int tid = threadIdx.x;
  int wv = tid >> 6;

  f32x4 cv = *(const f32x4*)(cls + (size_t)b * D_ + tid * 4);
  f32x4 yv[4];
#pragma unroll
  for (int rr = 0; rr < 4; rr++) {
    ((f32x4*)xs[rr])[tid] = *(const f32x4*)(X + (size_t)(row0 + rr) * D_ + tid * 4);
    yv[rr] = *(const f32x4*)(Y + (size_t)(row0 + rr) * D_ + tid * 4);
  }
  __syncthreads();

  // ---- stage 1: t1 = x @ A_s ----
  {
    int r = tid & 31, seg = tid >> 5;
    float a0 = 0.f, a1 = 0.f, a2 = 0.f, a3 = 0.f;
    const float* ap = A_s + r;
    for (int d = seg * 128; d < seg * 128 + 128; d++) {
      float w = ap[d * 32];
      a0 += xs[0][d] * w; a1 += xs[1][d] * w;
      a2 += xs[2][d] * w; a3 += xs[3][d] * w;
    }
    tp[seg][0][r] = a0; tp[seg][1][r] = a1; tp[seg][2][r] = a2; tp[seg][3][r] = a3;
  }
  __syncthreads();
  if (tid < 128) {
    int rr = tid >> 5, r = tid & 31;
    float sv = 0.f;
#pragma unroll
    for (int g = 0; g < 8; g++) sv += tp[g][rr][r];
    t1[rr][r] = sv;
  }
  __syncthreads();

  // ---- g = t1 @ B_s ; rms ; X' = scale*g*rs + Y ; pv = X' * cls ----
  f32x4 g[4] = {};
  for (int r = 0; r < 32; r++) {
    f32x4 bv = *(const f32x4*)(B_s + (size_t)r * D_ + tid * 4);
    g[0] += t1[0][r] * bv; g[1] += t1[1][r] * bv;
    g[2] += t1[2][r] * bv; g[3] += t1[3][r] * bv;
  }
  float ssl[4];
#pragma unroll
  for (int rr = 0; rr < 4; rr++)
    ssl[rr] = g[rr][0]*g[rr][0] + g[rr][1]*g[rr][1] + g[rr][2]*g[rr][2] + g[rr][3]*g[rr][3];
#pragma unroll
  for (int off = 1; off < 64; off <<= 1)
#pragma unroll
    for (int rr = 0; rr < 4; rr++) ssl[rr] += __shfl_xor(ssl[rr], off, 64);
  if ((tid & 63) == 0) {
#pragma unroll
    for (int rr = 0; rr < 4; rr++) red[wv][rr] = ssl[rr];
  }
  __syncthreads();
  {
    f32x4 scv = *(const f32x4*)(rms_s + tid * 4);
#pragma unroll
    for (int rr = 0; rr < 4; rr++) {
      float ss = red[0][rr] + red[1][rr] + red[2][rr] + red[3][rr];
      float rs = rsqrtf(ss * (1.f / D_) + 1e-6f);
      f32x4 xp = scv * g[rr] * rs + yv[rr];
      ((f32x4*)xs[rr])[tid] = xp * cv;
    }
  }
  __syncthreads();

  // ---- stage 2: t2 = (X'.cls) @ C_r ----
  {
    int r = tid & 31, seg = tid >> 5;
    float a0 = 0.f, a1 = 0.f, a2 = 0.f, a3 = 0.f;
    const float* cp = C_r + r;
    for (int d = seg * 128; d < seg * 128 + 128; d++) {
      float w = cp[d * 32];
      a0 += xs[0][d] * w; a1 += xs[1][d] * w;
      a2 += xs[2][d] * w; a3 += xs[3][d] * w;
    }
    tp[seg][0][r] = a0; tp[seg][1][r] = a1; tp[seg][2][r] = a2; tp[seg][3][r] = a3;
  }
  __syncthreads();
  if (tid < 128) {
    int rr = tid >> 5, r = tid & 31;
    float sv = 0.f;
#pragma unroll
    for (int g2i = 0; g2i < 8; g2i++) sv += tp[g2i][rr][r];
    t1[rr][r] = sv;
  }
  __syncthreads();

  // ---- g2 = t2 @ D_r ; rms -> z ----
  f32x4 g2[4] = {};
  for (int r = 0; r < 32; r++) {
    f32x4 bv = *(const f32x4*)(D_r + (size_t)r * D_ + tid * 4);
    g2[0] += t1[0][r] * bv; g2[1] += t1[1][r] * bv;
    g2[2] += t1[2][r] * bv; g2[3] += t1[3][r] * bv;
  }
#pragma unroll
  for (int rr = 0; rr < 4; rr++)
    ssl[rr] = g2[rr][0]*g2[rr][0] + g2[rr][1]*g2[rr][1] + g2[rr][2]*g2[rr][2] + g2[rr][3]*g2[rr][3];
#pragma unroll
  for (int off = 1; off < 64; off <<= 1)
#pragma unroll
    for (int rr = 0; rr < 4; rr++) ssl[rr] += __shfl_xor(ssl[rr], off, 64);
  if ((tid & 63) == 0) {
#pragma unroll
    for (int rr = 0; rr < 4; rr++) red[wv][rr] = ssl[rr];
  }
  __syncthreads();
  f32x4 z[4];
  {
    f32x4 scv = *(const f32x4*)(rms_c + tid * 4);
#pragma unroll
    for (int rr = 0; rr < 4; rr++) {
      float ss = red[0][rr] + red[1][rr] + red[2][rr] + red[3][rr];
      float rs = rsqrtf(ss * (1.f / D_) + 1e-6f);
      z[rr] = scv * g2[rr] * rs;
    }
  }

  // ---- LN + modulate of z -> znorm ----
  float s1l[4], s2l[4];
#pragma unroll
  for (int rr = 0; rr < 4; rr++) {
    s1l[rr] = z[rr][0] + z[rr][1] + z[rr][2] + z[rr][3];
    s2l[rr] = z[rr][0]*z[rr][0] + z[rr][1]*z[rr][1] + z[rr][2]*z[rr][2] + z[rr][3]*z[rr][3];
  }
#pragma unroll
  for (int off = 1; off < 64; off <<= 1)
#pragma unroll
    for (int rr = 0; rr < 4; rr++) {
      s1l[rr] += __shfl_xor(s1l[rr], off, 64);
      s2l[rr] += __shfl_xor(s2l[rr], off, 64);
    }
  if ((tid & 63) == 0) {
#pragma unroll
    for (int rr = 0; rr < 4; rr++) { red2[wv][rr][0] = s1l[rr]; red2[wv][rr][1] = s2l[rr]; }
  }
  __syncthreads();
  f32x4 shv = *(const f32x4*)(cproj + b * SIXD + 3072 + tid * 4);
  f32x4 scm = *(const f32x4*)(cproj + b * SIXD + 4096 + tid * 4);
#pragma unroll
  for (int rr = 0; rr < 4; rr++) {
    float S  = red2[0][rr][0] + red2[1][rr][0] + red2[2][rr][0] + red2[3][rr][0];
    float S2 = red2[0][rr][1] + red2[1][rr][1] + red2[2][rr][1] + red2[3][rr][1];
    float mean = S * (1.f / D_);
    float var  = S2 * (1.f / D_) - mean * mean;
    float rstd = rsqrtf(var + 1e-6f);
    f32x4 zn = (z[rr] - mean) * rstd * (scm + 1.f) + shv;
    *(f32x4*)(Z + (size_t)(row0 + rr) * D_ + tid * 4) = z[rr];
    bf16x4 o;
#pragma unroll
    for (int i = 0; i < 4; i++) o[i] = (__bf16)zn[i];
    *(bf16x4*)(Znorm + (size_t)(row0 + rr) * D_ + tid * 4) = o;
  }
}

// =====================================================================
extern "C" void kernel_launch(void* const* d_in, const int* in_sizes, int n_in,
                              void* d_out, int out_size, void* d_ws, size_t ws_size,
                              hipStream_t stream)
{
  const float* x     = (const float*)d_in[0];
  const float* c     = (const float*)d_in[1];
  const float* cls   = (const float*)d_in[2];
  const float* Wc    = (const float*)d_in[3];
  const float* bc    = (const float*)d_in[4];
  const float* Wqkv  = (const float*)d_in[5];
  const float* bqkv  = (const float*)d_in[6];
  const float* Wo    = (const float*)d_in[7];
  const float* bo    = (const float*)d_in[8];
  const float* A_s   = (const float*)d_in[9];
  const float* B_s   = (const float*)d_in[10];
  const float* rms_s = (const float*)d_in[11];
  const float* C_r   = (const float*)d_in[12];
  const float* D_r   = (const float*)d_in[13];
  const float* rms_c = (const float*)d_in[14];
  const float* W1    = (const float*)d_in[15];
  const float* b1    = (const float*)d_in[16];
  const float* W2    = (const float*)d_in[17];
  const float* b2    = (const float*)d_in[18];
  float* out = (float*)d_out;

  float* ws = (float*)d_ws;
  __bf16* Wqkvt = (__bf16*)(ws + 0);         // 3072x1024 bf16  [floats 0..1572864)
  __bf16* Wot   = (__bf16*)(ws + 1572864);   // 1024x1024       [..2097152)
  __bf16* W1t   = (__bf16*)(ws + 2097152);   // 4096x1024       [..4194304)
  __bf16* W2t   = (__bf16*)(ws + 4194304);   // 1024x4096       [..6291456)
  float*  cproj = ws + 6291456;              // 4x6144          [..6316032)
  __bf16* xnorm = (__bf16*)(ws + 6316032);   // 4096x1024 (also znorm)  [..8413184)
  __bf16* qkv   = (__bf16*)(ws + 8413184);   // 4096x3072       [..14704640)
  __bf16* Vt    = (__bf16*)(ws + 14704640);  // 64x64x1024      [..16801792)
  __bf16* h1    = (__bf16*)(ws + 8413184);   // 4096x4096 (reuses qkv+Vt)
  __bf16* attno = (__bf16*)(ws + 16801792);  // 4096x1024       [..18898944)
  float*  Ybuf  = ws + 18898944;             // 4096x1024 f32 (Y)  [..20996096)
  // W2 split-K(4) bf16 partials, 8 MB each, in regions dead at W2-GEMM time.
  // W2t [4194304..6291456) and h1 [8413184..16801792) are NOT touched.
  __bf16* P0 = (__bf16*)(ws + 0);            // over Wqkvt+Wot (dead)
  __bf16* P1 = (__bf16*)(ws + 2097152);      // over W1t (dead after W1 GEMM)
  __bf16* P2 = (__bf16*)(ws + 16801792);     // over attno (dead after Wo GEMM)
  __bf16* P3 = (__bf16*)(ws + 18898944);     // over Ybuf (dead after gram_fused)

  prep<<<960, 256, 0, stream>>>(c, Wc, bc, cproj,
                                Wqkv, Wo, W1, W2, Wqkvt, Wot, W1t, W2t);
  ln_mod<<<4096, 256, 0, stream>>>(x, cproj, 0, 1024, xnorm);
  gemm256<5, 16, 1024><<<192, 512, 0, stream>>>(xnorm, Wqkvt, bqkv,
                                                qkv, Vt, nullptr, nullptr,
                                                4096, 3072);
  attn_flash<<<512, 512, 0, stream>>>(qkv, Vt, attno);
  gemm_bt<1, 4><<<256, 256, 0, stream>>>(attno, Wot, bo, cproj, 2048, x,
                                         Ybuf, nullptr, nullptr, nullptr,
                                         4096, 1024, 1024, 1);
  gram_fused<<<1024, 256, 0, stream>>>(x, Ybuf, cls, A_s, B_s, rms_s,
                                       C_r, D_r, rms_c, cproj, out, xnorm);
  gemm256<2, 16, 1024><<<256, 512, 0, stream>>>(xnorm, W1t, b1,
                                                h1, nullptr, nullptr, nullptr,
                                                4096, 4096);
  gemm256<3, 16, 4096><<<256, 512, 0, stream>>>(h1, W2t, nullptr,
                                                P0, P1, P2, P3, 4096, 1024);
  reduce_w2<<<4096, 256, 0, stream>>>(P0, P1, P2, P3, b2, cproj, out);
}